// Round 9
// baseline (492.528 us; speedup 1.0000x reference)
//
#include <hip/hip_runtime.h>
#include <hip/hip_bf16.h>
#include <hip/hip_cooperative_groups.h>
#include <math.h>

namespace cg = cooperative_groups;

#define SEQ 8192
#define DIN 512
#define DH  64
#define SG  8                 // sequence splits
#define CHUNK (SEQ / SG)      // 1024 K-rows per flash sub-block
#define BK  64                // K/V rows per iteration
#define NIT (CHUNK / BK)      // 16 iterations
#define LDP 72                // padded LDS row stride (bf16)
#define SXP 516               // padded fp32 x row stride (pgemm)

typedef float f32x4 __attribute__((ext_vector_type(4)));
typedef short short8 __attribute__((ext_vector_type(8)));
typedef ushort us4 __attribute__((ext_vector_type(4)));

static __device__ __forceinline__ ushort bf16_of(float v) {
  __hip_bfloat16 h = __float2bfloat16(v);
  return *reinterpret_cast<ushort*>(&h);
}
static __device__ __forceinline__ float f_of_bf16(ushort u) {
  __hip_bfloat16 h;
  *reinterpret_cast<ushort*>(&h) = u;
  return __bfloat162float(h);
}
static __device__ __forceinline__ f32x4 mfma16(short8 a, short8 b, f32x4 c) {
  return __builtin_amdgcn_mfma_f32_16x16x32_bf16(a, b, c, 0, 0, 0);
}
static __device__ __forceinline__ uint pack_bf16(float a, float b) {
  __hip_bfloat162 h2 = __float22bfloat162_rn(make_float2(a, b));
  return *reinterpret_cast<uint*>(&h2);
}

// ===========================================================================
// Phase bodies (shared by the fused cooperative kernel and the 4-kernel
// fallback).  Byte-identical logic to R8 — single experimental variable
// this round is the fusion itself.
// ===========================================================================

static __device__ __forceinline__ void prep_body(
    char* smem, int bid, int tid,
    const float* __restrict__ Wq, const float* __restrict__ Wk,
    const float* __restrict__ Wv, ushort* __restrict__ Wth,
    ushort* __restrict__ Wtl) {
  float (*sw)[65] = reinterpret_cast<float(*)[65]>(smem);   // 16.6 KB
  const int mat = bid >> 3;
  const int kc  = bid & 7;
  const float* W = (mat == 0) ? Wq : ((mat == 1) ? Wk : Wv);
  const float scale = (mat == 0) ? 0.125f * 1.44269504088896f : 1.0f;
#pragma unroll
  for (int j = 0; j < 16; ++j) {
    const int i = tid + 256 * j;                    // 0..4095
    sw[i >> 6][i & 63] =
        W[(size_t)(kc * 64 + (i >> 6)) * 64 + (i & 63)] * scale;
  }
  __syncthreads();
  const int n  = tid >> 2;
  const int ks = (tid & 3) * 16;
  ushort hb[16] __attribute__((aligned(16)));
  ushort lb[16] __attribute__((aligned(16)));
#pragma unroll
  for (int j = 0; j < 16; ++j) {
    const float w = sw[ks + j][n];
    const ushort h = bf16_of(w);
    hb[j] = h;
    lb[j] = bf16_of(w - f_of_bf16(h));
  }
  const size_t base = (size_t)mat * 64 * 512 + (size_t)n * 512 + kc * 64 + ks;
  *reinterpret_cast<short8*>(Wth + base)     = *reinterpret_cast<short8*>(hb);
  *reinterpret_cast<short8*>(Wth + base + 8) = *reinterpret_cast<short8*>(hb + 8);
  *reinterpret_cast<short8*>(Wtl + base)     = *reinterpret_cast<short8*>(lb);
  *reinterpret_cast<short8*>(Wtl + base + 8) = *reinterpret_cast<short8*>(lb + 8);
}

static __device__ __forceinline__ void pgemm_body(
    char* smem, int bid, int tid,
    const float* __restrict__ x, const ushort* __restrict__ Wth,
    const ushort* __restrict__ Wtl,
    ushort* __restrict__ Qh, ushort* __restrict__ Ql,
    ushort* __restrict__ Kh, ushort* __restrict__ Kl,
    ushort* __restrict__ Vt) {
  float (*sx)[SXP] = reinterpret_cast<float(*)[SXP]>(smem);  // 33 KB
  float* mb = &sx[0][0];

  const int wv = tid >> 6, lane = tid & 63;
  const int ln = lane & 15, qd = lane >> 4;
  const int rb = bid * 16;

  {
    const float4* xg = reinterpret_cast<const float4*>(x + (size_t)rb * DIN);
#pragma unroll
    for (int j = 0; j < 8; ++j) {
      const int idx = tid + 256 * j;
      const int row = idx >> 7;
      const int col = (idx & 127) * 4;
      *reinterpret_cast<float4*>(&sx[row][col]) = xg[idx];
    }
  }
  __syncthreads();

  f32x4 acc[3][4];
#pragma unroll
  for (int m = 0; m < 3; ++m)
#pragma unroll
    for (int nt = 0; nt < 4; ++nt)
#pragma unroll
      for (int i = 0; i < 4; ++i) acc[m][nt][i] = 0.f;

  const int kb = wv * 128;
  for (int kt = 0; kt < 4; ++kt) {
    const int k0 = kb + kt * 32;
    float xs[8];
    *reinterpret_cast<float4*>(xs) =
        *reinterpret_cast<const float4*>(&sx[ln][k0 + qd * 8]);
    *reinterpret_cast<float4*>(xs + 4) =
        *reinterpret_cast<const float4*>(&sx[ln][k0 + qd * 8 + 4]);
    ushort ah[8] __attribute__((aligned(16)));
    ushort al[8] __attribute__((aligned(16)));
#pragma unroll
    for (int j = 0; j < 8; ++j) {
      const ushort h = bf16_of(xs[j]);
      ah[j] = h;
      al[j] = bf16_of(xs[j] - f_of_bf16(h));
    }
    const short8 Ah = *reinterpret_cast<short8*>(ah);
    const short8 Al = *reinterpret_cast<short8*>(al);
#pragma unroll
    for (int m = 0; m < 3; ++m) {
      const ushort* Wh = Wth + (size_t)m * 64 * 512;
      const ushort* Wl = Wtl + (size_t)m * 64 * 512;
#pragma unroll
      for (int nt = 0; nt < 4; ++nt) {
        const size_t wo = (size_t)(nt * 16 + ln) * 512 + k0 + qd * 8;
        const short8 bh = *reinterpret_cast<const short8*>(Wh + wo);
        const short8 bl = *reinterpret_cast<const short8*>(Wl + wo);
        acc[m][nt] = mfma16(Ah, bh, acc[m][nt]);
        acc[m][nt] = mfma16(Ah, bl, acc[m][nt]);
        acc[m][nt] = mfma16(Al, bh, acc[m][nt]);
      }
    }
  }

  const int eidx = (qd * 4) * 64 + ln;
  __syncthreads();
  if (wv >= 2) {
    float* b = mb + (size_t)(wv - 2) * 3072;
#pragma unroll
    for (int m = 0; m < 3; ++m)
#pragma unroll
      for (int nt = 0; nt < 4; ++nt)
#pragma unroll
        for (int r = 0; r < 4; ++r)
          b[m * 1024 + eidx + r * 64 + nt * 16] = acc[m][nt][r];
  }
  __syncthreads();
  if (wv < 2) {
    const float* b = mb + (size_t)wv * 3072;
#pragma unroll
    for (int m = 0; m < 3; ++m)
#pragma unroll
      for (int nt = 0; nt < 4; ++nt)
#pragma unroll
        for (int r = 0; r < 4; ++r)
          acc[m][nt][r] += b[m * 1024 + eidx + r * 64 + nt * 16];
  }
  __syncthreads();
  if (wv == 1) {
#pragma unroll
    for (int m = 0; m < 3; ++m)
#pragma unroll
      for (int nt = 0; nt < 4; ++nt)
#pragma unroll
        for (int r = 0; r < 4; ++r)
          mb[m * 1024 + eidx + r * 64 + nt * 16] = acc[m][nt][r];
  }
  __syncthreads();
  if (wv == 0) {
#pragma unroll
    for (int m = 0; m < 3; ++m)
#pragma unroll
      for (int nt = 0; nt < 4; ++nt)
#pragma unroll
        for (int r = 0; r < 4; ++r)
          acc[m][nt][r] += mb[m * 1024 + eidx + r * 64 + nt * 16];

#pragma unroll
    for (int m = 0; m < 2; ++m) {
      ushort* H = (m == 0) ? Qh : Kh;
      ushort* L = (m == 0) ? Ql : Kl;
#pragma unroll
      for (int nt = 0; nt < 4; ++nt)
#pragma unroll
        for (int r = 0; r < 4; ++r) {
          const float v = acc[m][nt][r];
          const int row = rb + qd * 4 + r;
          const int col = nt * 16 + ln;
          const ushort h = bf16_of(v);
          H[(size_t)row * DH + col] = h;
          L[(size_t)row * DH + col] = bf16_of(v - f_of_bf16(h));
        }
    }
#pragma unroll
    for (int nt = 0; nt < 4; ++nt) {
      ushort vp[4] __attribute__((aligned(8)));
#pragma unroll
      for (int r = 0; r < 4; ++r) vp[r] = bf16_of(acc[2][nt][r]);
      *reinterpret_cast<us4*>(Vt + (size_t)(nt * 16 + ln) * SEQ + rb + qd * 4) =
          *reinterpret_cast<us4*>(vp);
    }
  }
}

static __device__ __forceinline__ void flash_body(
    char* smem, int fb, int tid,
    const ushort* __restrict__ Qh, const ushort* __restrict__ Ql,
    const ushort* __restrict__ Kh, const ushort* __restrict__ Kl,
    const ushort* __restrict__ Vt,
    ushort* __restrict__ Opart, float* __restrict__ Mpart,
    float* __restrict__ Lpart) {
  ushort (*sKh)[LDP] = reinterpret_cast<ushort(*)[LDP]>(smem);           // 9.2 KB
  ushort (*sKl)[LDP] = reinterpret_cast<ushort(*)[LDP]>(smem + 9216);    // 9.2 KB
  ushort (*sVt)[LDP] = reinterpret_cast<ushort(*)[LDP]>(smem + 18432);   // 9.2 KB

  const int wv   = tid >> 6;
  const int lane = tid & 63;
  const int ln   = lane & 15;
  const int qd   = lane >> 4;
  const int sg   = fb & 7;
  const int qt   = fb >> 3;         // 0..127 (64-row Q tiles)
  const int qrow0  = qt * 64 + wv * 16;
  const int k0base = sg * CHUNK;

  const int r0 = tid >> 3, g0 = (tid & 7) * 8;
  const int r1 = r0 + 32,  g1 = g0;

  const int sA = ((qd & 1) * 2) * 16 + ln;   // gather src lane, j>>2 == 0
  const int sB = sA + 16;                    // j>>2 == 1
  const bool hiQd = (qd >= 2);

  const ushort one_u = (ln == 0) ? (ushort)0x3F80 : (ushort)0;
  short8 afr1;
#pragma unroll
  for (int j = 0; j < 8; ++j) afr1[j] = (short)one_u;

  short8 bqh[2], bql[2];
#pragma unroll
  for (int kt = 0; kt < 2; ++kt) {
    bqh[kt] = *reinterpret_cast<const short8*>(
        Qh + (size_t)(qrow0 + ln) * DH + kt * 32 + qd * 8);
    bql[kt] = *reinterpret_cast<const short8*>(
        Ql + (size_t)(qrow0 + ln) * DH + kt * 32 + qd * 8 - qd * 8 + qd * 8);
  }
  // (expression kept simple below — reload cleanly)
#pragma unroll
  for (int kt = 0; kt < 2; ++kt) {
    bql[kt] = *reinterpret_cast<const short8*>(
        Ql + (size_t)(qrow0 + ln) * DH + kt * 32 + qd * 8);
  }

  f32x4 accO[4], accL;
  float m_run = -INFINITY;
#pragma unroll
  for (int nt = 0; nt < 4; ++nt)
#pragma unroll
    for (int i = 0; i < 4; ++i) accO[nt][i] = 0.f;
#pragma unroll
  for (int i = 0; i < 4; ++i) accL[i] = 0.f;

  uint4 pk0, pk1, pl0, pl1, pv0, pv1;
#define LOAD_TILES(k0_)                                                        \
  do {                                                                         \
    pk0 = *reinterpret_cast<const uint4*>(Kh + (size_t)((k0_) + r0) * DH + g0);\
    pk1 = *reinterpret_cast<const uint4*>(Kh + (size_t)((k0_) + r1) * DH + g1);\
    pl0 = *reinterpret_cast<const uint4*>(Kl + (size_t)((k0_) + r0) * DH + g0);\
    pl1 = *reinterpret_cast<const uint4*>(Kl + (size_t)((k0_) + r1) * DH + g1);\
    pv0 = *reinterpret_cast<const uint4*>(Vt + (size_t)r0 * SEQ + (k0_) + g0); \
    pv1 = *reinterpret_cast<const uint4*>(Vt + (size_t)r1 * SEQ + (k0_) + g1); \
  } while (0)

  LOAD_TILES(k0base);

  for (int it = 0; it < NIT; ++it) {
    *reinterpret_cast<uint4*>(&sKh[r0][g0]) = pk0;
    *reinterpret_cast<uint4*>(&sKh[r1][g1]) = pk1;
    *reinterpret_cast<uint4*>(&sKl[r0][g0]) = pl0;
    *reinterpret_cast<uint4*>(&sKl[r1][g1]) = pl1;
    *reinterpret_cast<uint4*>(&sVt[r0][g0]) = pv0;
    *reinterpret_cast<uint4*>(&sVt[r1][g1]) = pv1;
    __syncthreads();

    const int k0n = k0base + ((it + 1 < NIT) ? (it + 1) : (NIT - 1)) * BK;
    LOAD_TILES(k0n);

    // S^T tile (64x16): A = K rows (LDS), B = Q (regs).  3-pass split.
    f32x4 accS[4];
#pragma unroll
    for (int nt = 0; nt < 4; ++nt) {
#pragma unroll
      for (int i = 0; i < 4; ++i) accS[nt][i] = 0.f;
      const short8 kh0 = *reinterpret_cast<const short8*>(&sKh[nt * 16 + ln][qd * 8]);
      const short8 kh1 = *reinterpret_cast<const short8*>(&sKh[nt * 16 + ln][32 + qd * 8]);
      const short8 kl0 = *reinterpret_cast<const short8*>(&sKl[nt * 16 + ln][qd * 8]);
      const short8 kl1 = *reinterpret_cast<const short8*>(&sKl[nt * 16 + ln][32 + qd * 8]);
      accS[nt] = mfma16(kh0, bqh[0], accS[nt]);
      accS[nt] = mfma16(kh1, bqh[1], accS[nt]);
      accS[nt] = mfma16(kh0, bql[0], accS[nt]);
      accS[nt] = mfma16(kh1, bql[1], accS[nt]);
      accS[nt] = mfma16(kl0, bqh[0], accS[nt]);
      accS[nt] = mfma16(kl1, bqh[1], accS[nt]);
    }

    // per-lane online softmax (lane owns q-row = ln), exp2 domain
    float tmax = fmaxf(fmaxf(fmaxf(accS[0][0], accS[0][1]), fmaxf(accS[0][2], accS[0][3])),
                       fmaxf(fmaxf(accS[1][0], accS[1][1]), fmaxf(accS[1][2], accS[1][3])));
    tmax = fmaxf(tmax,
                 fmaxf(fmaxf(fmaxf(accS[2][0], accS[2][1]), fmaxf(accS[2][2], accS[2][3])),
                       fmaxf(fmaxf(accS[3][0], accS[3][1]), fmaxf(accS[3][2], accS[3][3]))));
    tmax = fmaxf(tmax, __shfl_xor(tmax, 16));
    tmax = fmaxf(tmax, __shfl_xor(tmax, 32));
    const float mnew  = fmaxf(m_run, tmax);
    const float alpha = exp2f(m_run - mnew);
    m_run = mnew;

    uint pkd[4][2];
#pragma unroll
    for (int nt = 0; nt < 4; ++nt) {
      const float p0 = exp2f(accS[nt][0] - mnew);
      const float p1 = exp2f(accS[nt][1] - mnew);
      const float p2 = exp2f(accS[nt][2] - mnew);
      const float p3 = exp2f(accS[nt][3] - mnew);
      pkd[nt][0] = pack_bf16(p0, p1);
      pkd[nt][1] = pack_bf16(p2, p3);
#pragma unroll
      for (int i = 0; i < 4; ++i) accO[nt][i] *= alpha;
    }
    accL[0] *= alpha;

    // O^T += V^T · P^T ; l += 1~ · P^T  (dest-side select gather, R8-proven)
#pragma unroll
    for (int kt2 = 0; kt2 < 2; ++kt2) {
      const uint pA0 = pkd[kt2 * 2][0],     pA1 = pkd[kt2 * 2][1];
      const uint pB0 = pkd[kt2 * 2 + 1][0], pB1 = pkd[kt2 * 2 + 1][1];
      uint4 du;
      {
        const uint xA = (uint)__shfl((int)pA0, sA);
        const uint xB = (uint)__shfl((int)pB0, sA);
        du.x = hiQd ? xB : xA;
        const uint yA = (uint)__shfl((int)pA1, sA);
        const uint yB = (uint)__shfl((int)pB1, sA);
        du.y = hiQd ? yB : yA;
        const uint zA = (uint)__shfl((int)pA0, sB);
        const uint zB = (uint)__shfl((int)pB0, sB);
        du.z = hiQd ? zB : zA;
        const uint wA = (uint)__shfl((int)pA1, sB);
        const uint wB = (uint)__shfl((int)pB1, sB);
        du.w = hiQd ? wB : wA;
      }
      const short8 pfrag = *reinterpret_cast<short8*>(&du);
#pragma unroll
      for (int nt2 = 0; nt2 < 4; ++nt2) {
        const short8 vA = *reinterpret_cast<const short8*>(
            &sVt[nt2 * 16 + ln][kt2 * 32 + qd * 8]);
        accO[nt2] = mfma16(vA, pfrag, accO[nt2]);
      }
      accL = mfma16(afr1, pfrag, accL);
    }
    __syncthreads();
  }
#undef LOAD_TILES

  const int qrow = qrow0 + ln;
  ushort* Ob = Opart + ((size_t)sg * SEQ + qrow) * DH;
#pragma unroll
  for (int nt = 0; nt < 4; ++nt) {
    ushort op[4] __attribute__((aligned(8)));
#pragma unroll
    for (int r = 0; r < 4; ++r) op[r] = bf16_of(accO[nt][r]);
    *reinterpret_cast<us4*>(Ob + nt * 16 + qd * 4) =
        *reinterpret_cast<us4*>(op);
  }
  if (qd == 0) {
    Mpart[(size_t)sg * SEQ + qrow] = m_run;
    Lpart[(size_t)sg * SEQ + qrow] = accL[0];
  }
}

static __device__ __forceinline__ void merge_body(
    int bid, int tid,
    const ushort* __restrict__ Opart, const float* __restrict__ Mpart,
    const float* __restrict__ Lpart, float* __restrict__ out) {
  const int idx = bid * 256 + tid;   // 0 .. SEQ*16
  const int row = idx >> 4;
  const int c4  = (idx & 15) * 4;

  float m[SG];
  float M = -INFINITY;
#pragma unroll
  for (int i = 0; i < SG; ++i) {
    m[i] = Mpart[(size_t)i * SEQ + row];
    M = fmaxf(M, m[i]);
  }
  float L = 0.f;
  float a0 = 0.f, a1 = 0.f, a2 = 0.f, a3 = 0.f;
#pragma unroll
  for (int i = 0; i < SG; ++i) {
    const float w = exp2f(m[i] - M);
    L += w * Lpart[(size_t)i * SEQ + row];
    const us4 o = *reinterpret_cast<const us4*>(
        Opart + ((size_t)i * SEQ + row) * DH + c4);
    a0 += w * f_of_bf16(o[0]);
    a1 += w * f_of_bf16(o[1]);
    a2 += w * f_of_bf16(o[2]);
    a3 += w * f_of_bf16(o[3]);
  }
  const float rL = 1.0f / L;
  float4 res = make_float4(a0 * rL, a1 * rL, a2 * rL, a3 * rL);
  *reinterpret_cast<float4*>(out + (size_t)row * DH + c4) = res;
}

// ===========================================================================
// Fused cooperative kernel: grid 512 x 256.  LDS union 33 KB, 2 blocks/CU
// guaranteed by __launch_bounds__(256,2) (VGPR cap 256, LDS 66 KB < 160).
// grid.sync() + __threadfence() between phases (cross-XCD visibility).
// ===========================================================================
__global__ __launch_bounds__(256, 2) void fused_kernel(
    const float* __restrict__ x,  const float* __restrict__ Wq,
    const float* __restrict__ Wk, const float* __restrict__ Wv,
    ushort* __restrict__ Wth, ushort* __restrict__ Wtl,
    ushort* __restrict__ Qh, ushort* __restrict__ Ql,
    ushort* __restrict__ Kh, ushort* __restrict__ Kl,
    ushort* __restrict__ Vt,
    ushort* __restrict__ Opart, float* __restrict__ Mpart,
    float* __restrict__ Lpart, float* __restrict__ out) {
  __shared__ __attribute__((aligned(16))) char smem[33024];
  cg::grid_group grid = cg::this_grid();
  const int bid = blockIdx.x;
  const int tid = threadIdx.x;

  // phase 0: W transpose + split (blocks 0..23)
  if (bid < 24) prep_body(smem, bid, tid, Wq, Wk, Wv, Wth, Wtl);
  __threadfence();
  grid.sync();

  // phase 1: projections
  pgemm_body(smem, bid, tid, x, Wth, Wtl, Qh, Ql, Kh, Kl, Vt);
  __threadfence();
  grid.sync();

  // phase 2: flash partials (2 sub-blocks per coop block = 1024 tiles)
  flash_body(smem, bid, tid, Qh, Ql, Kh, Kl, Vt, Opart, Mpart, Lpart);
  __syncthreads();
  flash_body(smem, bid + 512, tid, Qh, Ql, Kh, Kl, Vt, Opart, Mpart, Lpart);
  __threadfence();
  grid.sync();

  // phase 3: merge + normalize
  merge_body(bid, tid, Opart, Mpart, Lpart, out);
}

// ===========================================================================
// Fallback standalone kernels (identical bodies) in case cooperative launch
// is rejected (e.g. under graph capture on some stacks).
// ===========================================================================
__global__ __launch_bounds__(256) void prep_kernel(
    const float* __restrict__ Wq, const float* __restrict__ Wk,
    const float* __restrict__ Wv, ushort* __restrict__ Wth,
    ushort* __restrict__ Wtl) {
  __shared__ __attribute__((aligned(16))) char smem[16640];
  prep_body(smem, blockIdx.x, threadIdx.x, Wq, Wk, Wv, Wth, Wtl);
}
__global__ __launch_bounds__(256, 2) void pgemm_kernel(
    const float* __restrict__ x, const ushort* __restrict__ Wth,
    const ushort* __restrict__ Wtl,
    ushort* __restrict__ Qh, ushort* __restrict__ Ql,
    ushort* __restrict__ Kh, ushort* __restrict__ Kl,
    ushort* __restrict__ Vt) {
  __shared__ __attribute__((aligned(16))) char smem[33024];
  pgemm_body(smem, blockIdx.x, threadIdx.x, x, Wth, Wtl, Qh, Ql, Kh, Kl, Vt);
}
__global__ __launch_bounds__(256, 4) void flash_kernel(
    const ushort* __restrict__ Qh, const ushort* __restrict__ Ql,
    const ushort* __restrict__ Kh, const ushort* __restrict__ Kl,
    const ushort* __restrict__ Vt,
    ushort* __restrict__ Opart, float* __restrict__ Mpart,
    float* __restrict__ Lpart) {
  __shared__ __attribute__((aligned(16))) char smem[27648];
  flash_body(smem, blockIdx.x, threadIdx.x, Qh, Ql, Kh, Kl, Vt, Opart, Mpart, Lpart);
}
__global__ __launch_bounds__(256) void merge_kernel(
    const ushort* __restrict__ Opart, const float* __restrict__ Mpart,
    const float* __restrict__ Lpart, float* __restrict__ out) {
  merge_body(blockIdx.x, threadIdx.x, Opart, Mpart, Lpart, out);
}

// ===========================================================================
extern "C" void kernel_launch(void* const* d_in, const int* in_sizes, int n_in,
                              void* d_out, int out_size, void* d_ws, size_t ws_size,
                              hipStream_t stream) {
  const float* x  = (const float*)d_in[0];
  const float* Wq = (const float*)d_in[1];
  const float* Wk = (const float*)d_in[2];
  const float* Wv = (const float*)d_in[3];
  float* out = (float*)d_out;

  // workspace layout — total 14,155,776 B (round-2..8-proven size).
  const size_t S64 = (size_t)SEQ * DH;        // 524288
  ushort* Qh = (ushort*)d_ws;
  ushort* Ql = Qh + S64;
  ushort* Kh = Ql + S64;
  ushort* Kl = Kh + S64;
  ushort* Vt = Kl + S64;
  ushort* Op = Vt + S64;                      // [SG][SEQ][DH] bf16
  ushort* Wth = Op;                           // alias (3*64*512 elems)
  ushort* Wtl = Wth + (size_t)3 * 64 * 512;
  float*  Mp = (float*)(Op + (size_t)SG * S64);
  float*  Lp = Mp + (size_t)SG * SEQ;

  void* args[] = {(void*)&x,  (void*)&Wq, (void*)&Wk, (void*)&Wv,
                  (void*)&Wth, (void*)&Wtl,
                  (void*)&Qh, (void*)&Ql, (void*)&Kh, (void*)&Kl, (void*)&Vt,
                  (void*)&Op, (void*)&Mp, (void*)&Lp, (void*)&out};
  hipError_t err = hipLaunchCooperativeKernel(
      (const void*)fused_kernel, dim3(512), dim3(256), args, 0, stream);
  if (err != hipSuccess) {
    // fallback: 4-kernel R8 path (identical math)
    prep_kernel<<<24, 256, 0, stream>>>(Wq, Wk, Wv, Wth, Wtl);
    pgemm_kernel<<<SEQ / 16, 256, 0, stream>>>(x, Wth, Wtl, Qh, Ql, Kh, Kl, Vt);
    flash_kernel<<<(SEQ / 64) * SG, 256, 0, stream>>>(Qh, Ql, Kh, Kl, Vt, Op, Mp, Lp);
    merge_kernel<<<(SEQ * 16) / 256, 256, 0, stream>>>(Op, Mp, Lp, out);
  }
}

// Round 10
// 261.754 us; speedup vs baseline: 1.8816x; 1.8816x over previous
//
#include <hip/hip_runtime.h>
#include <hip/hip_bf16.h>
#include <math.h>

#define SEQ 8192
#define DIN 512
#define DH  64
#define SG  8                 // sequence splits
#define CHUNK (SEQ / SG)      // 1024 K-rows per flash block
#define BK  64                // K/V rows per iteration
#define NIT (CHUNK / BK)      // 16 iterations
#define LDP 72                // padded LDS row stride (bf16)
#define SXP 516               // padded fp32 x row stride (pgemm)

typedef float f32x4 __attribute__((ext_vector_type(4)));
typedef short short8 __attribute__((ext_vector_type(8)));
typedef ushort us4 __attribute__((ext_vector_type(4)));

static __device__ __forceinline__ ushort bf16_of(float v) {
  __hip_bfloat16 h = __float2bfloat16(v);
  return *reinterpret_cast<ushort*>(&h);
}
static __device__ __forceinline__ float f_of_bf16(ushort u) {
  __hip_bfloat16 h;
  *reinterpret_cast<ushort*>(&h) = u;
  return __bfloat162float(h);
}
static __device__ __forceinline__ f32x4 mfma16(short8 a, short8 b, f32x4 c) {
  return __builtin_amdgcn_mfma_f32_16x16x32_bf16(a, b, c, 0, 0, 0);
}
static __device__ __forceinline__ uint pack_bf16(float a, float b) {
  __hip_bfloat162 h2 = __float22bfloat162_rn(make_float2(a, b));
  return *reinterpret_cast<uint*>(&h2);
}

// ---------------------------------------------------------------------------
// Kernel 0 (prep): transpose + hi/lo-split W into Wt[mat][n][k] bf16.
// Q gets 0.125 * log2(e) folded in (exp2-domain softmax end-to-end).
// ---------------------------------------------------------------------------
__global__ __launch_bounds__(256) void prep_kernel(
    const float* __restrict__ Wq, const float* __restrict__ Wk,
    const float* __restrict__ Wv, ushort* __restrict__ Wth,
    ushort* __restrict__ Wtl) {
  __shared__ float sw[64][65];
  const int mat = blockIdx.x >> 3;
  const int kc  = blockIdx.x & 7;
  const float* W = (mat == 0) ? Wq : ((mat == 1) ? Wk : Wv);
  const float scale = (mat == 0) ? 0.125f * 1.44269504088896f : 1.0f;
  const int tid = threadIdx.x;
#pragma unroll
  for (int j = 0; j < 16; ++j) {
    const int i = tid + 256 * j;                    // 0..4095
    sw[i >> 6][i & 63] =
        W[(size_t)(kc * 64 + (i >> 6)) * 64 + (i & 63)] * scale;
  }
  __syncthreads();
  const int n  = tid >> 2;
  const int ks = (tid & 3) * 16;
  ushort hb[16] __attribute__((aligned(16)));
  ushort lb[16] __attribute__((aligned(16)));
#pragma unroll
  for (int j = 0; j < 16; ++j) {
    const float w = sw[ks + j][n];
    const ushort h = bf16_of(w);
    hb[j] = h;
    lb[j] = bf16_of(w - f_of_bf16(h));
  }
  const size_t base = (size_t)mat * 64 * 512 + (size_t)n * 512 + kc * 64 + ks;
  *reinterpret_cast<short8*>(Wth + base)     = *reinterpret_cast<short8*>(hb);
  *reinterpret_cast<short8*>(Wth + base + 8) = *reinterpret_cast<short8*>(hb + 8);
  *reinterpret_cast<short8*>(Wtl + base)     = *reinterpret_cast<short8*>(lb);
  *reinterpret_cast<short8*>(Wtl + base + 8) = *reinterpret_cast<short8*>(lb + 8);
}

// ---------------------------------------------------------------------------
// Kernel 1 (pgemm v3): R6 structure + REGISTER-PREFETCH decoupling of the
// W B-fragment loads (the R5 flash recipe).  12 (kt,m) groups, fully
// unrolled ping-pong: group g+1's 8 short8 loads issue before group g's 12
// MFMAs, hiding L2 latency under compute instead of serializing 12 JIT
// batches.  Also zeroes the 128 per-qt merge counters (block 0) — stream
// order guarantees visibility to flash.
// ---------------------------------------------------------------------------
__global__ __launch_bounds__(256, 2) void pgemm_kernel(
    const float* __restrict__ x, const ushort* __restrict__ Wth,
    const ushort* __restrict__ Wtl,
    ushort* __restrict__ Qh, ushort* __restrict__ Ql,
    ushort* __restrict__ Kh, ushort* __restrict__ Kl,
    ushort* __restrict__ Vt, int* __restrict__ qcnt) {
  __shared__ float sx[16][SXP];               // 33 KB; reused as merge buf
  float* mb = &sx[0][0];

  const int tid = threadIdx.x;
  const int wv = tid >> 6, lane = tid & 63;
  const int ln = lane & 15, qd = lane >> 4;
  const int rb = blockIdx.x * 16;

  if (blockIdx.x == 0 && tid < 128) qcnt[tid] = 0;

  {
    const float4* xg = reinterpret_cast<const float4*>(x + (size_t)rb * DIN);
#pragma unroll
    for (int j = 0; j < 8; ++j) {
      const int idx = tid + 256 * j;
      const int row = idx >> 7;
      const int col = (idx & 127) * 4;
      *reinterpret_cast<float4*>(&sx[row][col]) = xg[idx];
    }
  }
  __syncthreads();

  f32x4 acc[3][4];
#pragma unroll
  for (int m = 0; m < 3; ++m)
#pragma unroll
    for (int nt = 0; nt < 4; ++nt)
#pragma unroll
      for (int i = 0; i < 4; ++i) acc[m][nt][i] = 0.f;

  const int kb = wv * 128;

  short8 wb[2][8];
#define LDG(kt_, m_, buf_)                                                     \
  do {                                                                         \
    const int k0_ = kb + (kt_) * 32;                                           \
    const ushort* Wh_ = Wth + (size_t)(m_) * 64 * 512;                         \
    const ushort* Wl_ = Wtl + (size_t)(m_) * 64 * 512;                         \
    _Pragma("unroll") for (int nt = 0; nt < 4; ++nt) {                         \
      const size_t wo = (size_t)(nt * 16 + ln) * 512 + k0_ + qd * 8;           \
      wb[buf_][nt * 2]     = *reinterpret_cast<const short8*>(Wh_ + wo);       \
      wb[buf_][nt * 2 + 1] = *reinterpret_cast<const short8*>(Wl_ + wo);       \
    }                                                                          \
  } while (0)

  LDG(0, 0, 0);
#pragma unroll
  for (int kt = 0; kt < 4; ++kt) {
    // convert this kt's x slice to split-bf16 A fragments
    const int k0 = kb + kt * 32;
    float xs[8];
    *reinterpret_cast<float4*>(xs) =
        *reinterpret_cast<const float4*>(&sx[ln][k0 + qd * 8]);
    *reinterpret_cast<float4*>(xs + 4) =
        *reinterpret_cast<const float4*>(&sx[ln][k0 + qd * 8 + 4]);
    ushort ah[8] __attribute__((aligned(16)));
    ushort al[8] __attribute__((aligned(16)));
#pragma unroll
    for (int j = 0; j < 8; ++j) {
      const ushort h = bf16_of(xs[j]);
      ah[j] = h;
      al[j] = bf16_of(xs[j] - f_of_bf16(h));
    }
    const short8 Ah = *reinterpret_cast<short8*>(ah);
    const short8 Al = *reinterpret_cast<short8*>(al);
#pragma unroll
    for (int m = 0; m < 3; ++m) {
      const int g = kt * 3 + m;               // compile-time (both loops unrolled)
      const int buf = g & 1;
      if (g < 11) {
        const int gn = g + 1;
        LDG(gn / 3, gn % 3, buf ^ 1);         // prefetch next group
      }
#pragma unroll
      for (int nt = 0; nt < 4; ++nt) {
        acc[m][nt] = mfma16(Ah, wb[buf][nt * 2],     acc[m][nt]);
        acc[m][nt] = mfma16(Ah, wb[buf][nt * 2 + 1], acc[m][nt]);
        acc[m][nt] = mfma16(Al, wb[buf][nt * 2],     acc[m][nt]);
      }
    }
  }
#undef LDG

  // ---- merge the 4 k-quarter partials through LDS (pairwise tree) ---------
  const int eidx = (qd * 4) * 64 + ln;
  __syncthreads();
  if (wv >= 2) {
    float* b = mb + (size_t)(wv - 2) * 3072;
#pragma unroll
    for (int m = 0; m < 3; ++m)
#pragma unroll
      for (int nt = 0; nt < 4; ++nt)
#pragma unroll
        for (int r = 0; r < 4; ++r)
          b[m * 1024 + eidx + r * 64 + nt * 16] = acc[m][nt][r];
  }
  __syncthreads();
  if (wv < 2) {
    const float* b = mb + (size_t)wv * 3072;
#pragma unroll
    for (int m = 0; m < 3; ++m)
#pragma unroll
      for (int nt = 0; nt < 4; ++nt)
#pragma unroll
        for (int r = 0; r < 4; ++r)
          acc[m][nt][r] += b[m * 1024 + eidx + r * 64 + nt * 16];
  }
  __syncthreads();
  if (wv == 1) {
#pragma unroll
    for (int m = 0; m < 3; ++m)
#pragma unroll
      for (int nt = 0; nt < 4; ++nt)
#pragma unroll
        for (int r = 0; r < 4; ++r)
          mb[m * 1024 + eidx + r * 64 + nt * 16] = acc[m][nt][r];
  }
  __syncthreads();
  if (wv == 0) {
#pragma unroll
    for (int m = 0; m < 3; ++m)
#pragma unroll
      for (int nt = 0; nt < 4; ++nt)
#pragma unroll
        for (int r = 0; r < 4; ++r)
          acc[m][nt][r] += mb[m * 1024 + eidx + r * 64 + nt * 16];

#pragma unroll
    for (int m = 0; m < 2; ++m) {
      ushort* H = (m == 0) ? Qh : Kh;
      ushort* L = (m == 0) ? Ql : Kl;
#pragma unroll
      for (int nt = 0; nt < 4; ++nt)
#pragma unroll
        for (int r = 0; r < 4; ++r) {
          const float v = acc[m][nt][r];
          const int row = rb + qd * 4 + r;
          const int col = nt * 16 + ln;
          const ushort h = bf16_of(v);
          H[(size_t)row * DH + col] = h;
          L[(size_t)row * DH + col] = bf16_of(v - f_of_bf16(h));
        }
    }
#pragma unroll
    for (int nt = 0; nt < 4; ++nt) {
      ushort vp[4] __attribute__((aligned(8)));
#pragma unroll
      for (int r = 0; r < 4; ++r) vp[r] = bf16_of(acc[2][nt][r]);
      *reinterpret_cast<us4*>(Vt + (size_t)(nt * 16 + ln) * SEQ + rb + qd * 4) =
          *reinterpret_cast<us4*>(vp);
    }
  }
}

// ---------------------------------------------------------------------------
// Kernel 2 (flash, R8-proven body + fused merge tail): transposed score tile
// S^T = K·Q^T; per-lane softmax; in-register P^T gather (dest-side select);
// O^T = V^T·P^T; l via ones-A-frag MFMA.  After the partial stores each
// block fences + atomicAdd(qcnt[qt]); the 8th arrival merges the 8 seq-split
// partials for its 64 Q-rows and writes d_out — the separate merge dispatch
// is gone.
// ---------------------------------------------------------------------------
__global__ __launch_bounds__(256, 4) void flash_kernel(
    const ushort* __restrict__ Qh, const ushort* __restrict__ Ql,
    const ushort* __restrict__ Kh, const ushort* __restrict__ Kl,
    const ushort* __restrict__ Vt,
    ushort* __restrict__ Opart, float* __restrict__ Mpart,
    float* __restrict__ Lpart, int* __restrict__ qcnt,
    float* __restrict__ out) {
  __shared__ __attribute__((aligned(16))) ushort sKh[BK][LDP];   // 9.2 KB
  __shared__ __attribute__((aligned(16))) ushort sKl[BK][LDP];   // 9.2 KB
  __shared__ __attribute__((aligned(16))) ushort sVt[DH][LDP];   // 9.2 KB
  __shared__ int s_last;

  const int tid  = threadIdx.x;
  const int wv   = tid >> 6;
  const int lane = tid & 63;
  const int ln   = lane & 15;
  const int qd   = lane >> 4;
  const int bid  = blockIdx.x;
  const int sg   = bid & 7;
  const int qt   = bid >> 3;        // 0..127 (64-row Q tiles)
  const int qrow0  = qt * 64 + wv * 16;
  const int k0base = sg * CHUNK;

  const int r0 = tid >> 3, g0 = (tid & 7) * 8;
  const int r1 = r0 + 32,  g1 = g0;

  const int sA = ((qd & 1) * 2) * 16 + ln;   // gather src lane, j>>2 == 0
  const int sB = sA + 16;                    // j>>2 == 1
  const bool hiQd = (qd >= 2);

  const ushort one_u = (ln == 0) ? (ushort)0x3F80 : (ushort)0;
  short8 afr1;
#pragma unroll
  for (int j = 0; j < 8; ++j) afr1[j] = (short)one_u;

  short8 bqh[2], bql[2];
#pragma unroll
  for (int kt = 0; kt < 2; ++kt) {
    bqh[kt] = *reinterpret_cast<const short8*>(
        Qh + (size_t)(qrow0 + ln) * DH + kt * 32 + qd * 8);
    bql[kt] = *reinterpret_cast<const short8*>(
        Ql + (size_t)(qrow0 + ln) * DH + kt * 32 + qd * 8);
  }

  f32x4 accO[4], accL;
  float m_run = -INFINITY;
#pragma unroll
  for (int nt = 0; nt < 4; ++nt)
#pragma unroll
    for (int i = 0; i < 4; ++i) accO[nt][i] = 0.f;
#pragma unroll
  for (int i = 0; i < 4; ++i) accL[i] = 0.f;

  uint4 pk0, pk1, pl0, pl1, pv0, pv1;
#define LOAD_TILES(k0_)                                                        \
  do {                                                                         \
    pk0 = *reinterpret_cast<const uint4*>(Kh + (size_t)((k0_) + r0) * DH + g0);\
    pk1 = *reinterpret_cast<const uint4*>(Kh + (size_t)((k0_) + r1) * DH + g1);\
    pl0 = *reinterpret_cast<const uint4*>(Kl + (size_t)((k0_) + r0) * DH + g0);\
    pl1 = *reinterpret_cast<const uint4*>(Kl + (size_t)((k0_) + r1) * DH + g1);\
    pv0 = *reinterpret_cast<const uint4*>(Vt + (size_t)r0 * SEQ + (k0_) + g0); \
    pv1 = *reinterpret_cast<const uint4*>(Vt + (size_t)r1 * SEQ + (k0_) + g1); \
  } while (0)

  LOAD_TILES(k0base);

  for (int it = 0; it < NIT; ++it) {
    *reinterpret_cast<uint4*>(&sKh[r0][g0]) = pk0;
    *reinterpret_cast<uint4*>(&sKh[r1][g1]) = pk1;
    *reinterpret_cast<uint4*>(&sKl[r0][g0]) = pl0;
    *reinterpret_cast<uint4*>(&sKl[r1][g1]) = pl1;
    *reinterpret_cast<uint4*>(&sVt[r0][g0]) = pv0;
    *reinterpret_cast<uint4*>(&sVt[r1][g1]) = pv1;
    __syncthreads();

    const int k0n = k0base + ((it + 1 < NIT) ? (it + 1) : (NIT - 1)) * BK;
    LOAD_TILES(k0n);

    // S^T tile (64x16): A = K rows (LDS), B = Q (regs).  3-pass split.
    f32x4 accS[4];
#pragma unroll
    for (int nt = 0; nt < 4; ++nt) {
#pragma unroll
      for (int i = 0; i < 4; ++i) accS[nt][i] = 0.f;
      const short8 kh0 = *reinterpret_cast<const short8*>(&sKh[nt * 16 + ln][qd * 8]);
      const short8 kh1 = *reinterpret_cast<const short8*>(&sKh[nt * 16 + ln][32 + qd * 8]);
      const short8 kl0 = *reinterpret_cast<const short8*>(&sKl[nt * 16 + ln][qd * 8]);
      const short8 kl1 = *reinterpret_cast<const short8*>(&sKl[nt * 16 + ln][32 + qd * 8]);
      accS[nt] = mfma16(kh0, bqh[0], accS[nt]);
      accS[nt] = mfma16(kh1, bqh[1], accS[nt]);
      accS[nt] = mfma16(kh0, bql[0], accS[nt]);
      accS[nt] = mfma16(kh1, bql[1], accS[nt]);
      accS[nt] = mfma16(kl0, bqh[0], accS[nt]);
      accS[nt] = mfma16(kl1, bqh[1], accS[nt]);
    }

    // per-lane online softmax (lane owns q-row = ln), exp2 domain
    float tmax = fmaxf(fmaxf(fmaxf(accS[0][0], accS[0][1]), fmaxf(accS[0][2], accS[0][3])),
                       fmaxf(fmaxf(accS[1][0], accS[1][1]), fmaxf(accS[1][2], accS[1][3])));
    tmax = fmaxf(tmax,
                 fmaxf(fmaxf(fmaxf(accS[2][0], accS[2][1]), fmaxf(accS[2][2], accS[2][3])),
                       fmaxf(fmaxf(accS[3][0], accS[3][1]), fmaxf(accS[3][2], accS[3][3]))));
    tmax = fmaxf(tmax, __shfl_xor(tmax, 16));
    tmax = fmaxf(tmax, __shfl_xor(tmax, 32));
    const float mnew  = fmaxf(m_run, tmax);
    const float alpha = exp2f(m_run - mnew);
    m_run = mnew;

    uint pkd[4][2];
#pragma unroll
    for (int nt = 0; nt < 4; ++nt) {
      const float p0 = exp2f(accS[nt][0] - mnew);
      const float p1 = exp2f(accS[nt][1] - mnew);
      const float p2 = exp2f(accS[nt][2] - mnew);
      const float p3 = exp2f(accS[nt][3] - mnew);
      pkd[nt][0] = pack_bf16(p0, p1);
      pkd[nt][1] = pack_bf16(p2, p3);
#pragma unroll
      for (int i = 0; i < 4; ++i) accO[nt][i] *= alpha;
    }
    accL[0] *= alpha;

    // O^T += V^T · P^T ; l += 1~ · P^T  (dest-side select gather, R8-proven)
#pragma unroll
    for (int kt2 = 0; kt2 < 2; ++kt2) {
      const uint pA0 = pkd[kt2 * 2][0],     pA1 = pkd[kt2 * 2][1];
      const uint pB0 = pkd[kt2 * 2 + 1][0], pB1 = pkd[kt2 * 2 + 1][1];
      uint4 du;
      {
        const uint xA = (uint)__shfl((int)pA0, sA);
        const uint xB = (uint)__shfl((int)pB0, sA);
        du.x = hiQd ? xB : xA;
        const uint yA = (uint)__shfl((int)pA1, sA);
        const uint yB = (uint)__shfl((int)pB1, sA);
        du.y = hiQd ? yB : yA;
        const uint zA = (uint)__shfl((int)pA0, sB);
        const uint zB = (uint)__shfl((int)pB0, sB);
        du.z = hiQd ? zB : zA;
        const uint wA = (uint)__shfl((int)pA1, sB);
        const uint wB = (uint)__shfl((int)pB1, sB);
        du.w = hiQd ? wB : wA;
      }
      const short8 pfrag = *reinterpret_cast<short8*>(&du);
#pragma unroll
      for (int nt2 = 0; nt2 < 4; ++nt2) {
        const short8 vA = *reinterpret_cast<const short8*>(
            &sVt[nt2 * 16 + ln][kt2 * 32 + qd * 8]);
        accO[nt2] = mfma16(vA, pfrag, accO[nt2]);
      }
      accL = mfma16(afr1, pfrag, accL);
    }
    __syncthreads();
  }
#undef LOAD_TILES

  // ---- write partials ------------------------------------------------------
  const int qrow = qrow0 + ln;
  ushort* Ob = Opart + ((size_t)sg * SEQ + qrow) * DH;
#pragma unroll
  for (int nt = 0; nt < 4; ++nt) {
    ushort op[4] __attribute__((aligned(8)));
#pragma unroll
    for (int r = 0; r < 4; ++r) op[r] = bf16_of(accO[nt][r]);
    *reinterpret_cast<us4*>(Ob + nt * 16 + qd * 4) =
        *reinterpret_cast<us4*>(op);
  }
  if (qd == 0) {
    Mpart[(size_t)sg * SEQ + qrow] = m_run;
    Lpart[(size_t)sg * SEQ + qrow] = accL[0];
  }

  // ---- fused merge: 8th-arriving block for this qt merges its 64 rows -----
  __threadfence();            // partial stores visible device-wide
  __syncthreads();            // all threads' fences before the atomic
  if (tid == 0) {
    const int old = atomicAdd(&qcnt[qt], 1);
    s_last = (old == SG - 1) ? 1 : 0;
  }
  __syncthreads();
  if (s_last) {
#pragma unroll
    for (int j = 0; j < 4; ++j) {
      const int t   = tid + 256 * j;            // 0..1023
      const int row = qt * 64 + (t >> 4);
      const int c4  = (t & 15) * 4;
      float m[SG];
      float M = -INFINITY;
#pragma unroll
      for (int i = 0; i < SG; ++i) {
        m[i] = Mpart[(size_t)i * SEQ + row];
        M = fmaxf(M, m[i]);
      }
      float L = 0.f;
      float a0 = 0.f, a1 = 0.f, a2 = 0.f, a3 = 0.f;
#pragma unroll
      for (int i = 0; i < SG; ++i) {
        const float w = exp2f(m[i] - M);
        L += w * Lpart[(size_t)i * SEQ + row];
        const us4 o = *reinterpret_cast<const us4*>(
            Opart + ((size_t)i * SEQ + row) * DH + c4);
        a0 += w * f_of_bf16(o[0]);
        a1 += w * f_of_bf16(o[1]);
        a2 += w * f_of_bf16(o[2]);
        a3 += w * f_of_bf16(o[3]);
      }
      const float rL = 1.0f / L;
      float4 res = make_float4(a0 * rL, a1 * rL, a2 * rL, a3 * rL);
      *reinterpret_cast<float4*>(out + (size_t)row * DH + c4) = res;
    }
  }
}

// ---------------------------------------------------------------------------
extern "C" void kernel_launch(void* const* d_in, const int* in_sizes, int n_in,
                              void* d_out, int out_size, void* d_ws, size_t ws_size,
                              hipStream_t stream) {
  const float* x  = (const float*)d_in[0];
  const float* Wq = (const float*)d_in[1];
  const float* Wk = (const float*)d_in[2];
  const float* Wv = (const float*)d_in[3];
  float* out = (float*)d_out;

  // workspace layout — 14,155,776 B (R2..R8-proven) + 512 B merge counters.
  const size_t S64 = (size_t)SEQ * DH;        // 524288
  ushort* Qh = (ushort*)d_ws;
  ushort* Ql = Qh + S64;
  ushort* Kh = Ql + S64;
  ushort* Kl = Kh + S64;
  ushort* Vt = Kl + S64;
  ushort* Op = Vt + S64;                      // [SG][SEQ][DH] bf16
  ushort* Wth = Op;                           // alias (3*64*512 elems)
  ushort* Wtl = Wth + (size_t)3 * 64 * 512;
  float*  Mp = (float*)(Op + (size_t)SG * S64);
  float*  Lp = Mp + (size_t)SG * SEQ;
  int*    qcnt = (int*)(Lp + (size_t)SG * SEQ);   // 128 ints

  prep_kernel<<<24, 256, 0, stream>>>(Wq, Wk, Wv, Wth, Wtl);
  pgemm_kernel<<<SEQ / 16, 256, 0, stream>>>(x, Wth, Wtl, Qh, Ql, Kh, Kl, Vt, qcnt);
  flash_kernel<<<(SEQ / 64) * SG, 256, 0, stream>>>(Qh, Ql, Kh, Kl, Vt, Op, Mp, Lp, qcnt, out);
}

// Round 11
// 153.219 us; speedup vs baseline: 3.2145x; 1.7084x over previous
//
#include <hip/hip_runtime.h>
#include <hip/hip_bf16.h>
#include <math.h>

#define SEQ 8192
#define DIN 512
#define DH  64
#define SG  8                 // sequence splits
#define CHUNK (SEQ / SG)      // 1024 K-rows per flash block
#define BK  64                // K/V rows per iteration
#define NIT (CHUNK / BK)      // 16 iterations
#define LDP 72                // padded LDS row stride (bf16)
#define SXP 516               // padded fp32 x row stride (pgemm)

typedef float f32x4 __attribute__((ext_vector_type(4)));
typedef short short8 __attribute__((ext_vector_type(8)));
typedef ushort us4 __attribute__((ext_vector_type(4)));

static __device__ __forceinline__ ushort bf16_of(float v) {
  __hip_bfloat16 h = __float2bfloat16(v);
  return *reinterpret_cast<ushort*>(&h);
}
static __device__ __forceinline__ float f_of_bf16(ushort u) {
  __hip_bfloat16 h;
  *reinterpret_cast<ushort*>(&h) = u;
  return __bfloat162float(h);
}
static __device__ __forceinline__ f32x4 mfma16(short8 a, short8 b, f32x4 c) {
  return __builtin_amdgcn_mfma_f32_16x16x32_bf16(a, b, c, 0, 0, 0);
}
static __device__ __forceinline__ uint pack_bf16(float a, float b) {
  __hip_bfloat162 h2 = __float22bfloat162_rn(make_float2(a, b));
  return *reinterpret_cast<uint*>(&h2);
}

// ---------------------------------------------------------------------------
// Kernel 0 (prep): transpose + hi/lo-split W into Wt[mat][n][k] bf16.
// Q gets 0.125 * log2(e) folded in (exp2-domain softmax end-to-end).
// ---------------------------------------------------------------------------
__global__ __launch_bounds__(256) void prep_kernel(
    const float* __restrict__ Wq, const float* __restrict__ Wk,
    const float* __restrict__ Wv, ushort* __restrict__ Wth,
    ushort* __restrict__ Wtl) {
  __shared__ float sw[64][65];
  const int mat = blockIdx.x >> 3;
  const int kc  = blockIdx.x & 7;
  const float* W = (mat == 0) ? Wq : ((mat == 1) ? Wk : Wv);
  const float scale = (mat == 0) ? 0.125f * 1.44269504088896f : 1.0f;
  const int tid = threadIdx.x;
#pragma unroll
  for (int j = 0; j < 16; ++j) {
    const int i = tid + 256 * j;                    // 0..4095
    sw[i >> 6][i & 63] =
        W[(size_t)(kc * 64 + (i >> 6)) * 64 + (i & 63)] * scale;
  }
  __syncthreads();
  const int n  = tid >> 2;
  const int ks = (tid & 3) * 16;
  ushort hb[16] __attribute__((aligned(16)));
  ushort lb[16] __attribute__((aligned(16)));
#pragma unroll
  for (int j = 0; j < 16; ++j) {
    const float w = sw[ks + j][n];
    const ushort h = bf16_of(w);
    hb[j] = h;
    lb[j] = bf16_of(w - f_of_bf16(h));
  }
  const size_t base = (size_t)mat * 64 * 512 + (size_t)n * 512 + kc * 64 + ks;
  *reinterpret_cast<short8*>(Wth + base)     = *reinterpret_cast<short8*>(hb);
  *reinterpret_cast<short8*>(Wth + base + 8) = *reinterpret_cast<short8*>(hb + 8);
  *reinterpret_cast<short8*>(Wtl + base)     = *reinterpret_cast<short8*>(lb);
  *reinterpret_cast<short8*>(Wtl + base + 8) = *reinterpret_cast<short8*>(lb + 8);
}

// ---------------------------------------------------------------------------
// Kernel 1 (pgemm v3, R10-proven): split-bf16 MFMA projections with
// register-prefetch ping-pong on the W B-fragments (12 unrolled groups).
// ---------------------------------------------------------------------------
__global__ __launch_bounds__(256, 2) void pgemm_kernel(
    const float* __restrict__ x, const ushort* __restrict__ Wth,
    const ushort* __restrict__ Wtl,
    ushort* __restrict__ Qh, ushort* __restrict__ Ql,
    ushort* __restrict__ Kh, ushort* __restrict__ Kl,
    ushort* __restrict__ Vt) {
  __shared__ float sx[16][SXP];               // 33 KB; reused as merge buf
  float* mb = &sx[0][0];

  const int tid = threadIdx.x;
  const int wv = tid >> 6, lane = tid & 63;
  const int ln = lane & 15, qd = lane >> 4;
  const int rb = blockIdx.x * 16;

  {
    const float4* xg = reinterpret_cast<const float4*>(x + (size_t)rb * DIN);
#pragma unroll
    for (int j = 0; j < 8; ++j) {
      const int idx = tid + 256 * j;
      const int row = idx >> 7;
      const int col = (idx & 127) * 4;
      *reinterpret_cast<float4*>(&sx[row][col]) = xg[idx];
    }
  }
  __syncthreads();

  f32x4 acc[3][4];
#pragma unroll
  for (int m = 0; m < 3; ++m)
#pragma unroll
    for (int nt = 0; nt < 4; ++nt)
#pragma unroll
      for (int i = 0; i < 4; ++i) acc[m][nt][i] = 0.f;

  const int kb = wv * 128;

  short8 wb[2][8];
#define LDG(kt_, m_, buf_)                                                     \
  do {                                                                         \
    const int k0_ = kb + (kt_) * 32;                                           \
    const ushort* Wh_ = Wth + (size_t)(m_) * 64 * 512;                         \
    const ushort* Wl_ = Wtl + (size_t)(m_) * 64 * 512;                         \
    _Pragma("unroll") for (int nt = 0; nt < 4; ++nt) {                         \
      const size_t wo = (size_t)(nt * 16 + ln) * 512 + k0_ + qd * 8;           \
      wb[buf_][nt * 2]     = *reinterpret_cast<const short8*>(Wh_ + wo);       \
      wb[buf_][nt * 2 + 1] = *reinterpret_cast<const short8*>(Wl_ + wo);       \
    }                                                                          \
  } while (0)

  LDG(0, 0, 0);
#pragma unroll
  for (int kt = 0; kt < 4; ++kt) {
    const int k0 = kb + kt * 32;
    float xs[8];
    *reinterpret_cast<float4*>(xs) =
        *reinterpret_cast<const float4*>(&sx[ln][k0 + qd * 8]);
    *reinterpret_cast<float4*>(xs + 4) =
        *reinterpret_cast<const float4*>(&sx[ln][k0 + qd * 8 + 4]);
    ushort ah[8] __attribute__((aligned(16)));
    ushort al[8] __attribute__((aligned(16)));
#pragma unroll
    for (int j = 0; j < 8; ++j) {
      const ushort h = bf16_of(xs[j]);
      ah[j] = h;
      al[j] = bf16_of(xs[j] - f_of_bf16(h));
    }
    const short8 Ah = *reinterpret_cast<short8*>(ah);
    const short8 Al = *reinterpret_cast<short8*>(al);
#pragma unroll
    for (int m = 0; m < 3; ++m) {
      const int g = kt * 3 + m;               // compile-time
      const int buf = g & 1;
      if (g < 11) {
        const int gn = g + 1;
        LDG(gn / 3, gn % 3, buf ^ 1);         // prefetch next group
      }
#pragma unroll
      for (int nt = 0; nt < 4; ++nt) {
        acc[m][nt] = mfma16(Ah, wb[buf][nt * 2],     acc[m][nt]);
        acc[m][nt] = mfma16(Ah, wb[buf][nt * 2 + 1], acc[m][nt]);
        acc[m][nt] = mfma16(Al, wb[buf][nt * 2],     acc[m][nt]);
      }
    }
  }
#undef LDG

  const int eidx = (qd * 4) * 64 + ln;
  __syncthreads();
  if (wv >= 2) {
    float* b = mb + (size_t)(wv - 2) * 3072;
#pragma unroll
    for (int m = 0; m < 3; ++m)
#pragma unroll
      for (int nt = 0; nt < 4; ++nt)
#pragma unroll
        for (int r = 0; r < 4; ++r)
          b[m * 1024 + eidx + r * 64 + nt * 16] = acc[m][nt][r];
  }
  __syncthreads();
  if (wv < 2) {
    const float* b = mb + (size_t)wv * 3072;
#pragma unroll
    for (int m = 0; m < 3; ++m)
#pragma unroll
      for (int nt = 0; nt < 4; ++nt)
#pragma unroll
        for (int r = 0; r < 4; ++r)
          acc[m][nt][r] += b[m * 1024 + eidx + r * 64 + nt * 16];
  }
  __syncthreads();
  if (wv == 1) {
#pragma unroll
    for (int m = 0; m < 3; ++m)
#pragma unroll
      for (int nt = 0; nt < 4; ++nt)
#pragma unroll
        for (int r = 0; r < 4; ++r)
          mb[m * 1024 + eidx + r * 64 + nt * 16] = acc[m][nt][r];
  }
  __syncthreads();
  if (wv == 0) {
#pragma unroll
    for (int m = 0; m < 3; ++m)
#pragma unroll
      for (int nt = 0; nt < 4; ++nt)
#pragma unroll
        for (int r = 0; r < 4; ++r)
          acc[m][nt][r] += mb[m * 1024 + eidx + r * 64 + nt * 16];

#pragma unroll
    for (int m = 0; m < 2; ++m) {
      ushort* H = (m == 0) ? Qh : Kh;
      ushort* L = (m == 0) ? Ql : Kl;
#pragma unroll
      for (int nt = 0; nt < 4; ++nt)
#pragma unroll
        for (int r = 0; r < 4; ++r) {
          const float v = acc[m][nt][r];
          const int row = rb + qd * 4 + r;
          const int col = nt * 16 + ln;
          const ushort h = bf16_of(v);
          H[(size_t)row * DH + col] = h;
          L[(size_t)row * DH + col] = bf16_of(v - f_of_bf16(h));
        }
    }
#pragma unroll
    for (int nt = 0; nt < 4; ++nt) {
      ushort vp[4] __attribute__((aligned(8)));
#pragma unroll
      for (int r = 0; r < 4; ++r) vp[r] = bf16_of(acc[2][nt][r]);
      *reinterpret_cast<us4*>(Vt + (size_t)(nt * 16 + ln) * SEQ + rb + qd * 4) =
          *reinterpret_cast<us4*>(vp);
    }
  }
}

// ---------------------------------------------------------------------------
// Kernel 2 (flash v4): TWO Q-SETS PER WAVE.  R8's flash is LDS-issue-bound
// (~30 ds instrs/iter/wave x 12 cyc = ~92k cyc/CU of the 158k total).  Each
// wave now owns 32 Q-rows as two 16-row S^T tiles: every K-fragment LDS read
// feeds 12 MFMAs (was 6), every V-fragment read feeds 2 (was 1) -> LDS
// instructions per unit of work halve; MFMA/VALU totals unchanged.
// Grid 512 = 64 qtiles(128 rows) x 8 sg; 2 blocks/CU (launch_bounds(256,2),
// ~180 VGPR < 256 cap -> no spills).  NO device fences / atomics in this
// kernel (R10 lesson: device-scope fence = XCD-L2 writeback poison).
// Transposed formulation, per-lane softmax, dest-side-select P^T gather and
// ones-A-frag l accumulation are all R8-proven.
// ---------------------------------------------------------------------------
__global__ __launch_bounds__(256, 2) void flash_kernel(
    const ushort* __restrict__ Qh, const ushort* __restrict__ Ql,
    const ushort* __restrict__ Kh, const ushort* __restrict__ Kl,
    const ushort* __restrict__ Vt,
    ushort* __restrict__ Opart, float* __restrict__ Mpart,
    float* __restrict__ Lpart) {
  __shared__ __attribute__((aligned(16))) ushort sKh[BK][LDP];   // 9.2 KB
  __shared__ __attribute__((aligned(16))) ushort sKl[BK][LDP];   // 9.2 KB
  __shared__ __attribute__((aligned(16))) ushort sVt[DH][LDP];   // 9.2 KB

  const int tid  = threadIdx.x;
  const int wv   = tid >> 6;
  const int lane = tid & 63;
  const int ln   = lane & 15;
  const int qd   = lane >> 4;
  const int bid  = blockIdx.x;
  const int sg   = bid & 7;         // XCD-aligned seq split
  const int qt   = bid >> 3;        // 0..63 (128-row Q tiles)
  const int qrow0  = qt * 128 + wv * 32;   // set s adds s*16
  const int k0base = sg * CHUNK;

  const int r0 = tid >> 3, g0 = (tid & 7) * 8;
  const int r1 = r0 + 32,  g1 = g0;

  const int sA = ((qd & 1) * 2) * 16 + ln;   // gather src lane, j>>2 == 0
  const int sB = sA + 16;                    // j>>2 == 1
  const bool hiQd = (qd >= 2);

  const ushort one_u = (ln == 0) ? (ushort)0x3F80 : (ushort)0;
  short8 afr1;
#pragma unroll
  for (int j = 0; j < 8; ++j) afr1[j] = (short)one_u;

  // Q fragments (B-operand), both sets, loaded once
  short8 bqh[2][2], bql[2][2];
#pragma unroll
  for (int s = 0; s < 2; ++s)
#pragma unroll
    for (int kt = 0; kt < 2; ++kt) {
      bqh[s][kt] = *reinterpret_cast<const short8*>(
          Qh + (size_t)(qrow0 + s * 16 + ln) * DH + kt * 32 + qd * 8);
      bql[s][kt] = *reinterpret_cast<const short8*>(
          Ql + (size_t)(qrow0 + s * 16 + ln) * DH + kt * 32 + qd * 8);
    }

  f32x4 accO[2][4], accL[2];
  float m_run[2] = {-INFINITY, -INFINITY};
#pragma unroll
  for (int s = 0; s < 2; ++s) {
#pragma unroll
    for (int nt = 0; nt < 4; ++nt)
#pragma unroll
      for (int i = 0; i < 4; ++i) accO[s][nt][i] = 0.f;
#pragma unroll
    for (int i = 0; i < 4; ++i) accL[s][i] = 0.f;
  }

  uint4 pk0, pk1, pl0, pl1, pv0, pv1;
#define LOAD_TILES(k0_)                                                        \
  do {                                                                         \
    pk0 = *reinterpret_cast<const uint4*>(Kh + (size_t)((k0_) + r0) * DH + g0);\
    pk1 = *reinterpret_cast<const uint4*>(Kh + (size_t)((k0_) + r1) * DH + g1);\
    pl0 = *reinterpret_cast<const uint4*>(Kl + (size_t)((k0_) + r0) * DH + g0);\
    pl1 = *reinterpret_cast<const uint4*>(Kl + (size_t)((k0_) + r1) * DH + g1);\
    pv0 = *reinterpret_cast<const uint4*>(Vt + (size_t)r0 * SEQ + (k0_) + g0); \
    pv1 = *reinterpret_cast<const uint4*>(Vt + (size_t)r1 * SEQ + (k0_) + g1); \
  } while (0)

  LOAD_TILES(k0base);

  for (int it = 0; it < NIT; ++it) {
    *reinterpret_cast<uint4*>(&sKh[r0][g0]) = pk0;
    *reinterpret_cast<uint4*>(&sKh[r1][g1]) = pk1;
    *reinterpret_cast<uint4*>(&sKl[r0][g0]) = pl0;
    *reinterpret_cast<uint4*>(&sKl[r1][g1]) = pl1;
    *reinterpret_cast<uint4*>(&sVt[r0][g0]) = pv0;
    *reinterpret_cast<uint4*>(&sVt[r1][g1]) = pv1;
    __syncthreads();

    const int k0n = k0base + ((it + 1 < NIT) ? (it + 1) : (NIT - 1)) * BK;
    LOAD_TILES(k0n);

    // S^T tiles (64x16 per set): each K-fragment read feeds both sets
    f32x4 accS[2][4];
#pragma unroll
    for (int nt = 0; nt < 4; ++nt) {
#pragma unroll
      for (int s = 0; s < 2; ++s)
#pragma unroll
        for (int i = 0; i < 4; ++i) accS[s][nt][i] = 0.f;
      const short8 kh0 = *reinterpret_cast<const short8*>(&sKh[nt * 16 + ln][qd * 8]);
      const short8 kh1 = *reinterpret_cast<const short8*>(&sKh[nt * 16 + ln][32 + qd * 8]);
      const short8 kl0 = *reinterpret_cast<const short8*>(&sKl[nt * 16 + ln][qd * 8]);
      const short8 kl1 = *reinterpret_cast<const short8*>(&sKl[nt * 16 + ln][32 + qd * 8]);
#pragma unroll
      for (int s = 0; s < 2; ++s) {
        accS[s][nt] = mfma16(kh0, bqh[s][0], accS[s][nt]);
        accS[s][nt] = mfma16(kh1, bqh[s][1], accS[s][nt]);
        accS[s][nt] = mfma16(kh0, bql[s][0], accS[s][nt]);
        accS[s][nt] = mfma16(kh1, bql[s][1], accS[s][nt]);
        accS[s][nt] = mfma16(kl0, bqh[s][0], accS[s][nt]);
        accS[s][nt] = mfma16(kl1, bqh[s][1], accS[s][nt]);
      }
    }

    // per-lane online softmax (lane owns q-row = ln of its set), exp2 domain
    uint pkd[2][4][2];
#pragma unroll
    for (int s = 0; s < 2; ++s) {
      float tmax = fmaxf(
          fmaxf(fmaxf(accS[s][0][0], accS[s][0][1]), fmaxf(accS[s][0][2], accS[s][0][3])),
          fmaxf(fmaxf(accS[s][1][0], accS[s][1][1]), fmaxf(accS[s][1][2], accS[s][1][3])));
      tmax = fmaxf(tmax, fmaxf(
          fmaxf(fmaxf(accS[s][2][0], accS[s][2][1]), fmaxf(accS[s][2][2], accS[s][2][3])),
          fmaxf(fmaxf(accS[s][3][0], accS[s][3][1]), fmaxf(accS[s][3][2], accS[s][3][3]))));
      tmax = fmaxf(tmax, __shfl_xor(tmax, 16));
      tmax = fmaxf(tmax, __shfl_xor(tmax, 32));
      const float mnew  = fmaxf(m_run[s], tmax);
      const float alpha = exp2f(m_run[s] - mnew);
      m_run[s] = mnew;
#pragma unroll
      for (int nt = 0; nt < 4; ++nt) {
        const float p0 = exp2f(accS[s][nt][0] - mnew);
        const float p1 = exp2f(accS[s][nt][1] - mnew);
        const float p2 = exp2f(accS[s][nt][2] - mnew);
        const float p3 = exp2f(accS[s][nt][3] - mnew);
        pkd[s][nt][0] = pack_bf16(p0, p1);
        pkd[s][nt][1] = pack_bf16(p2, p3);
#pragma unroll
        for (int i = 0; i < 4; ++i) accO[s][nt][i] *= alpha;
      }
      accL[s][0] *= alpha;
    }

    // O^T += V^T · P^T ; l += 1~ · P^T — each V read feeds both sets
#pragma unroll
    for (int kt2 = 0; kt2 < 2; ++kt2) {
      short8 pfrag[2];
#pragma unroll
      for (int s = 0; s < 2; ++s) {
        const uint pA0 = pkd[s][kt2 * 2][0],     pA1 = pkd[s][kt2 * 2][1];
        const uint pB0 = pkd[s][kt2 * 2 + 1][0], pB1 = pkd[s][kt2 * 2 + 1][1];
        uint4 du;
        const uint xA = (uint)__shfl((int)pA0, sA);
        const uint xB = (uint)__shfl((int)pB0, sA);
        du.x = hiQd ? xB : xA;
        const uint yA = (uint)__shfl((int)pA1, sA);
        const uint yB = (uint)__shfl((int)pB1, sA);
        du.y = hiQd ? yB : yA;
        const uint zA = (uint)__shfl((int)pA0, sB);
        const uint zB = (uint)__shfl((int)pB0, sB);
        du.z = hiQd ? zB : zA;
        const uint wA = (uint)__shfl((int)pA1, sB);
        const uint wB = (uint)__shfl((int)pB1, sB);
        du.w = hiQd ? wB : wA;
        pfrag[s] = *reinterpret_cast<short8*>(&du);
      }
#pragma unroll
      for (int nt2 = 0; nt2 < 4; ++nt2) {
        const short8 vA = *reinterpret_cast<const short8*>(
            &sVt[nt2 * 16 + ln][kt2 * 32 + qd * 8]);
        accO[0][nt2] = mfma16(vA, pfrag[0], accO[0][nt2]);
        accO[1][nt2] = mfma16(vA, pfrag[1], accO[1][nt2]);
      }
      accL[0] = mfma16(afr1, pfrag[0], accL[0]);
      accL[1] = mfma16(afr1, pfrag[1], accL[1]);
    }
    __syncthreads();
  }
#undef LOAD_TILES

  // epilogue per set: lane holds q-row = qrow0 + s*16 + ln
#pragma unroll
  for (int s = 0; s < 2; ++s) {
    const int qrow = qrow0 + s * 16 + ln;
    ushort* Ob = Opart + ((size_t)sg * SEQ + qrow) * DH;
#pragma unroll
    for (int nt = 0; nt < 4; ++nt) {
      ushort op[4] __attribute__((aligned(8)));
#pragma unroll
      for (int r = 0; r < 4; ++r) op[r] = bf16_of(accO[s][nt][r]);
      *reinterpret_cast<us4*>(Ob + nt * 16 + qd * 4) =
          *reinterpret_cast<us4*>(op);
    }
    if (qd == 0) {
      Mpart[(size_t)sg * SEQ + qrow] = m_run[s];
      Lpart[(size_t)sg * SEQ + qrow] = accL[s][0];
    }
  }
}

// ---------------------------------------------------------------------------
// Kernel 3: merge of the 8 seq-split partials (exp2 domain), vectorized x4.
// Separate dispatch on purpose — cross-XCD reduction behind a kernel
// boundary, no device fences in hot kernels (R10 lesson).
// ---------------------------------------------------------------------------
__global__ __launch_bounds__(256) void merge_kernel(
    const ushort* __restrict__ Opart, const float* __restrict__ Mpart,
    const float* __restrict__ Lpart, float* __restrict__ out) {
  const int idx = blockIdx.x * 256 + threadIdx.x;   // 0 .. SEQ*16
  const int row = idx >> 4;
  const int c4  = (idx & 15) * 4;

  float m[SG];
  float M = -INFINITY;
#pragma unroll
  for (int i = 0; i < SG; ++i) {
    m[i] = Mpart[(size_t)i * SEQ + row];
    M = fmaxf(M, m[i]);
  }
  float L = 0.f;
  float a0 = 0.f, a1 = 0.f, a2 = 0.f, a3 = 0.f;
#pragma unroll
  for (int i = 0; i < SG; ++i) {
    const float w = exp2f(m[i] - M);
    L += w * Lpart[(size_t)i * SEQ + row];
    const us4 o = *reinterpret_cast<const us4*>(
        Opart + ((size_t)i * SEQ + row) * DH + c4);
    a0 += w * f_of_bf16(o[0]);
    a1 += w * f_of_bf16(o[1]);
    a2 += w * f_of_bf16(o[2]);
    a3 += w * f_of_bf16(o[3]);
  }
  const float rL = 1.0f / L;
  float4 res = make_float4(a0 * rL, a1 * rL, a2 * rL, a3 * rL);
  *reinterpret_cast<float4*>(out + (size_t)row * DH + c4) = res;
}

// ---------------------------------------------------------------------------
extern "C" void kernel_launch(void* const* d_in, const int* in_sizes, int n_in,
                              void* d_out, int out_size, void* d_ws, size_t ws_size,
                              hipStream_t stream) {
  const float* x  = (const float*)d_in[0];
  const float* Wq = (const float*)d_in[1];
  const float* Wk = (const float*)d_in[2];
  const float* Wv = (const float*)d_in[3];
  float* out = (float*)d_out;

  // workspace layout — 14,155,776 B (R2..R8-proven size).
  const size_t S64 = (size_t)SEQ * DH;        // 524288
  ushort* Qh = (ushort*)d_ws;
  ushort* Ql = Qh + S64;
  ushort* Kh = Ql + S64;
  ushort* Kl = Kh + S64;
  ushort* Vt = Kl + S64;
  ushort* Op = Vt + S64;                      // [SG][SEQ][DH] bf16
  ushort* Wth = Op;                           // alias (3*64*512 elems)
  ushort* Wtl = Wth + (size_t)3 * 64 * 512;
  float*  Mp = (float*)(Op + (size_t)SG * S64);
  float*  Lp = Mp + (size_t)SG * SEQ;

  prep_kernel<<<24, 256, 0, stream>>>(Wq, Wk, Wv, Wth, Wtl);
  pgemm_kernel<<<SEQ / 16, 256, 0, stream>>>(x, Wth, Wtl, Qh, Ql, Kh, Kl, Vt);
  flash_kernel<<<(SEQ / 128) * SG, 256, 0, stream>>>(Qh, Ql, Kh, Kl, Vt, Op, Mp, Lp);
  merge_kernel<<<(SEQ * 16) / 256, 256, 0, stream>>>(Op, Mp, Lp, out);
}

// Round 12
// 143.211 us; speedup vs baseline: 3.4392x; 1.0699x over previous
//
#include <hip/hip_runtime.h>
#include <hip/hip_bf16.h>
#include <math.h>

#define SEQ 8192
#define DIN 512
#define DH  64
#define SG  8                 // sequence splits
#define CHUNK (SEQ / SG)      // 1024 K-rows per flash block
#define BK  64                // K/V rows per iteration
#define NIT (CHUNK / BK)      // 16 iterations
#define LDP 72                // padded LDS row stride (bf16)
#define SXP 516               // padded fp32 x row stride (pgemm)

typedef float f32x4 __attribute__((ext_vector_type(4)));
typedef short short8 __attribute__((ext_vector_type(8)));
typedef ushort us4 __attribute__((ext_vector_type(4)));

static __device__ __forceinline__ ushort bf16_of(float v) {
  __hip_bfloat16 h = __float2bfloat16(v);
  return *reinterpret_cast<ushort*>(&h);
}
static __device__ __forceinline__ float f_of_bf16(ushort u) {
  __hip_bfloat16 h;
  *reinterpret_cast<ushort*>(&h) = u;
  return __bfloat162float(h);
}
static __device__ __forceinline__ f32x4 mfma16(short8 a, short8 b, f32x4 c) {
  return __builtin_amdgcn_mfma_f32_16x16x32_bf16(a, b, c, 0, 0, 0);
}
static __device__ __forceinline__ uint pack_bf16(float a, float b) {
  __hip_bfloat162 h2 = __float22bfloat162_rn(make_float2(a, b));
  return *reinterpret_cast<uint*>(&h2);
}
// K-row permutation: physical row p -> LDS slot, chosen so that the S^T
// C-layout ownership (qd owns rows qd*4+r per 16-block) coincides with the
// PV B-operand k-ownership (qd owns k=qd*8+j per 32-block).  Derivation:
// slot s = nt*16+qd*4+rr must hold physical k = (nt&1)*32 + qd*8 + (nt>>1)*4
// + rr; inverting gives slot_of below.  Verified: p=5 -> slot 33 -> accS[2][1]
// on qd=0 -> B-frag (kt2=0, j=5) = P^T[5][q].
static __device__ __forceinline__ int slot_of(int p) {
  return ((((p >> 2) & 1) * 2 + (p >> 5)) << 4) | (((p >> 3) & 3) << 2) | (p & 3);
}

// ---------------------------------------------------------------------------
// Kernel 0 (prep): transpose + hi/lo-split W into Wt[mat][n][k] bf16.
// Q gets 0.125 * log2(e) folded in (exp2-domain softmax end-to-end).
// ---------------------------------------------------------------------------
__global__ __launch_bounds__(256) void prep_kernel(
    const float* __restrict__ Wq, const float* __restrict__ Wk,
    const float* __restrict__ Wv, ushort* __restrict__ Wth,
    ushort* __restrict__ Wtl) {
  __shared__ float sw[64][65];
  const int mat = blockIdx.x >> 3;
  const int kc  = blockIdx.x & 7;
  const float* W = (mat == 0) ? Wq : ((mat == 1) ? Wk : Wv);
  const float scale = (mat == 0) ? 0.125f * 1.44269504088896f : 1.0f;
  const int tid = threadIdx.x;
#pragma unroll
  for (int j = 0; j < 16; ++j) {
    const int i = tid + 256 * j;                    // 0..4095
    sw[i >> 6][i & 63] =
        W[(size_t)(kc * 64 + (i >> 6)) * 64 + (i & 63)] * scale;
  }
  __syncthreads();
  const int n  = tid >> 2;
  const int ks = (tid & 3) * 16;
  ushort hb[16] __attribute__((aligned(16)));
  ushort lb[16] __attribute__((aligned(16)));
#pragma unroll
  for (int j = 0; j < 16; ++j) {
    const float w = sw[ks + j][n];
    const ushort h = bf16_of(w);
    hb[j] = h;
    lb[j] = bf16_of(w - f_of_bf16(h));
  }
  const size_t base = (size_t)mat * 64 * 512 + (size_t)n * 512 + kc * 64 + ks;
  *reinterpret_cast<short8*>(Wth + base)     = *reinterpret_cast<short8*>(hb);
  *reinterpret_cast<short8*>(Wth + base + 8) = *reinterpret_cast<short8*>(hb + 8);
  *reinterpret_cast<short8*>(Wtl + base)     = *reinterpret_cast<short8*>(lb);
  *reinterpret_cast<short8*>(Wtl + base + 8) = *reinterpret_cast<short8*>(lb + 8);
}

// ---------------------------------------------------------------------------
// Kernel 1 (pgemm v3, R10/R11-proven): split-bf16 MFMA projections with
// register-prefetch ping-pong on the W B-fragments (12 unrolled groups).
// ---------------------------------------------------------------------------
__global__ __launch_bounds__(256, 2) void pgemm_kernel(
    const float* __restrict__ x, const ushort* __restrict__ Wth,
    const ushort* __restrict__ Wtl,
    ushort* __restrict__ Qh, ushort* __restrict__ Ql,
    ushort* __restrict__ Kh, ushort* __restrict__ Kl,
    ushort* __restrict__ Vt) {
  __shared__ float sx[16][SXP];               // 33 KB; reused as merge buf
  float* mb = &sx[0][0];

  const int tid = threadIdx.x;
  const int wv = tid >> 6, lane = tid & 63;
  const int ln = lane & 15, qd = lane >> 4;
  const int rb = blockIdx.x * 16;

  {
    const float4* xg = reinterpret_cast<const float4*>(x + (size_t)rb * DIN);
#pragma unroll
    for (int j = 0; j < 8; ++j) {
      const int idx = tid + 256 * j;
      const int row = idx >> 7;
      const int col = (idx & 127) * 4;
      *reinterpret_cast<float4*>(&sx[row][col]) = xg[idx];
    }
  }
  __syncthreads();

  f32x4 acc[3][4];
#pragma unroll
  for (int m = 0; m < 3; ++m)
#pragma unroll
    for (int nt = 0; nt < 4; ++nt)
#pragma unroll
      for (int i = 0; i < 4; ++i) acc[m][nt][i] = 0.f;

  const int kb = wv * 128;

  short8 wb[2][8];
#define LDG(kt_, m_, buf_)                                                     \
  do {                                                                         \
    const int k0_ = kb + (kt_) * 32;                                           \
    const ushort* Wh_ = Wth + (size_t)(m_) * 64 * 512;                         \
    const ushort* Wl_ = Wtl + (size_t)(m_) * 64 * 512;                         \
    _Pragma("unroll") for (int nt = 0; nt < 4; ++nt) {                         \
      const size_t wo = (size_t)(nt * 16 + ln) * 512 + k0_ + qd * 8;           \
      wb[buf_][nt * 2]     = *reinterpret_cast<const short8*>(Wh_ + wo);       \
      wb[buf_][nt * 2 + 1] = *reinterpret_cast<const short8*>(Wl_ + wo);       \
    }                                                                          \
  } while (0)

  LDG(0, 0, 0);
#pragma unroll
  for (int kt = 0; kt < 4; ++kt) {
    const int k0 = kb + kt * 32;
    float xs[8];
    *reinterpret_cast<float4*>(xs) =
        *reinterpret_cast<const float4*>(&sx[ln][k0 + qd * 8]);
    *reinterpret_cast<float4*>(xs + 4) =
        *reinterpret_cast<const float4*>(&sx[ln][k0 + qd * 8 + 4]);
    ushort ah[8] __attribute__((aligned(16)));
    ushort al[8] __attribute__((aligned(16)));
#pragma unroll
    for (int j = 0; j < 8; ++j) {
      const ushort h = bf16_of(xs[j]);
      ah[j] = h;
      al[j] = bf16_of(xs[j] - f_of_bf16(h));
    }
    const short8 Ah = *reinterpret_cast<short8*>(ah);
    const short8 Al = *reinterpret_cast<short8*>(al);
#pragma unroll
    for (int m = 0; m < 3; ++m) {
      const int g = kt * 3 + m;               // compile-time
      const int buf = g & 1;
      if (g < 11) {
        const int gn = g + 1;
        LDG(gn / 3, gn % 3, buf ^ 1);         // prefetch next group
      }
#pragma unroll
      for (int nt = 0; nt < 4; ++nt) {
        acc[m][nt] = mfma16(Ah, wb[buf][nt * 2],     acc[m][nt]);
        acc[m][nt] = mfma16(Ah, wb[buf][nt * 2 + 1], acc[m][nt]);
        acc[m][nt] = mfma16(Al, wb[buf][nt * 2],     acc[m][nt]);
      }
    }
  }
#undef LDG

  const int eidx = (qd * 4) * 64 + ln;
  __syncthreads();
  if (wv >= 2) {
    float* b = mb + (size_t)(wv - 2) * 3072;
#pragma unroll
    for (int m = 0; m < 3; ++m)
#pragma unroll
      for (int nt = 0; nt < 4; ++nt)
#pragma unroll
        for (int r = 0; r < 4; ++r)
          b[m * 1024 + eidx + r * 64 + nt * 16] = acc[m][nt][r];
  }
  __syncthreads();
  if (wv < 2) {
    const float* b = mb + (size_t)wv * 3072;
#pragma unroll
    for (int m = 0; m < 3; ++m)
#pragma unroll
      for (int nt = 0; nt < 4; ++nt)
#pragma unroll
        for (int r = 0; r < 4; ++r)
          acc[m][nt][r] += b[m * 1024 + eidx + r * 64 + nt * 16];
  }
  __syncthreads();
  if (wv == 1) {
#pragma unroll
    for (int m = 0; m < 3; ++m)
#pragma unroll
      for (int nt = 0; nt < 4; ++nt)
#pragma unroll
        for (int r = 0; r < 4; ++r)
          mb[m * 1024 + eidx + r * 64 + nt * 16] = acc[m][nt][r];
  }
  __syncthreads();
  if (wv == 0) {
#pragma unroll
    for (int m = 0; m < 3; ++m)
#pragma unroll
      for (int nt = 0; nt < 4; ++nt)
#pragma unroll
        for (int r = 0; r < 4; ++r)
          acc[m][nt][r] += mb[m * 1024 + eidx + r * 64 + nt * 16];

#pragma unroll
    for (int m = 0; m < 2; ++m) {
      ushort* H = (m == 0) ? Qh : Kh;
      ushort* L = (m == 0) ? Ql : Kl;
#pragma unroll
      for (int nt = 0; nt < 4; ++nt)
#pragma unroll
        for (int r = 0; r < 4; ++r) {
          const float v = acc[m][nt][r];
          const int row = rb + qd * 4 + r;
          const int col = nt * 16 + ln;
          const ushort h = bf16_of(v);
          H[(size_t)row * DH + col] = h;
          L[(size_t)row * DH + col] = bf16_of(v - f_of_bf16(h));
        }
    }
#pragma unroll
    for (int nt = 0; nt < 4; ++nt) {
      ushort vp[4] __attribute__((aligned(8)));
#pragma unroll
      for (int r = 0; r < 4; ++r) vp[r] = bf16_of(acc[2][nt][r]);
      *reinterpret_cast<us4*>(Vt + (size_t)(nt * 16 + ln) * SEQ + rb + qd * 4) =
          *reinterpret_cast<us4*>(vp);
    }
  }
}

// ---------------------------------------------------------------------------
// Kernel 2 (flash v5): 2 Q-sets/wave + PERMUTED K STAGING (gather-free P^T)
// + double-buffered LDS (one barrier per iter).
// The P^T B-fragment for PV is now pure register renaming:
//   kt2 frag = {pkd[kt2][0], pkd[kt2][1], pkd[kt2+2][0], pkd[kt2+2][1]}
// — the 32 ds_bpermute + 16 cndmask per wave-iter of R11 are deleted.
// Softmax max/sum and PV/L accumulation are K-row-order invariant, so the
// permutation needs no compensation anywhere else.
// ---------------------------------------------------------------------------
__global__ __launch_bounds__(256, 2) void flash_kernel(
    const ushort* __restrict__ Qh, const ushort* __restrict__ Ql,
    const ushort* __restrict__ Kh, const ushort* __restrict__ Kl,
    const ushort* __restrict__ Vt,
    ushort* __restrict__ Opart, float* __restrict__ Mpart,
    float* __restrict__ Lpart) {
  __shared__ __attribute__((aligned(16))) ushort sKh[2][BK][LDP];  // 18.4 KB
  __shared__ __attribute__((aligned(16))) ushort sKl[2][BK][LDP];  // 18.4 KB
  __shared__ __attribute__((aligned(16))) ushort sVt[2][DH][LDP];  // 18.4 KB

  const int tid  = threadIdx.x;
  const int wv   = tid >> 6;
  const int lane = tid & 63;
  const int ln   = lane & 15;
  const int qd   = lane >> 4;
  const int bid  = blockIdx.x;
  const int sg   = bid & 7;
  const int qt   = bid >> 3;        // 0..63 (128-row Q tiles)
  const int qrow0  = qt * 128 + wv * 32;   // set s adds s*16
  const int k0base = sg * CHUNK;

  const int r0 = tid >> 3, g0 = (tid & 7) * 8;
  const int r1 = r0 + 32,  g1 = g0;
  const int sr0 = slot_of(r0), sr1 = slot_of(r1);   // permuted K slots

  const ushort one_u = (ln == 0) ? (ushort)0x3F80 : (ushort)0;
  short8 afr1;
#pragma unroll
  for (int j = 0; j < 8; ++j) afr1[j] = (short)one_u;

  // Q fragments (B-operand), both sets, loaded once
  short8 bqh[2][2], bql[2][2];
#pragma unroll
  for (int s = 0; s < 2; ++s)
#pragma unroll
    for (int kt = 0; kt < 2; ++kt) {
      bqh[s][kt] = *reinterpret_cast<const short8*>(
          Qh + (size_t)(qrow0 + s * 16 + ln) * DH + kt * 32 + qd * 8);
      bql[s][kt] = *reinterpret_cast<const short8*>(
          Ql + (size_t)(qrow0 + s * 16 + ln) * DH + kt * 32 + qd * 8);
    }

  f32x4 accO[2][4], accL[2];
  float m_run[2] = {-INFINITY, -INFINITY};
#pragma unroll
  for (int s = 0; s < 2; ++s) {
#pragma unroll
    for (int nt = 0; nt < 4; ++nt)
#pragma unroll
      for (int i = 0; i < 4; ++i) accO[s][nt][i] = 0.f;
#pragma unroll
    for (int i = 0; i < 4; ++i) accL[s][i] = 0.f;
  }

  uint4 pk0, pk1, pl0, pl1, pv0, pv1;
#define LOAD_TILES(k0_)                                                        \
  do {                                                                         \
    pk0 = *reinterpret_cast<const uint4*>(Kh + (size_t)((k0_) + r0) * DH + g0);\
    pk1 = *reinterpret_cast<const uint4*>(Kh + (size_t)((k0_) + r1) * DH + g1);\
    pl0 = *reinterpret_cast<const uint4*>(Kl + (size_t)((k0_) + r0) * DH + g0);\
    pl1 = *reinterpret_cast<const uint4*>(Kl + (size_t)((k0_) + r1) * DH + g1);\
    pv0 = *reinterpret_cast<const uint4*>(Vt + (size_t)r0 * SEQ + (k0_) + g0); \
    pv1 = *reinterpret_cast<const uint4*>(Vt + (size_t)r1 * SEQ + (k0_) + g1); \
  } while (0)
#define STORE_TILES(b_)                                                        \
  do {                                                                         \
    *reinterpret_cast<uint4*>(&sKh[b_][sr0][g0]) = pk0;                        \
    *reinterpret_cast<uint4*>(&sKh[b_][sr1][g1]) = pk1;                        \
    *reinterpret_cast<uint4*>(&sKl[b_][sr0][g0]) = pl0;                        \
    *reinterpret_cast<uint4*>(&sKl[b_][sr1][g1]) = pl1;                        \
    *reinterpret_cast<uint4*>(&sVt[b_][r0][g0])  = pv0;                        \
    *reinterpret_cast<uint4*>(&sVt[b_][r1][g1])  = pv1;                        \
  } while (0)

  LOAD_TILES(k0base);
  STORE_TILES(0);
  __syncthreads();

  for (int it = 0; it < NIT; ++it) {
    const int cur = it & 1;
    const int k0n = k0base + ((it + 1 < NIT) ? (it + 1) : it) * BK;
    LOAD_TILES(k0n);          // global loads for next iter, hidden by compute

    // S^T tiles (64x16 per set): each K-fragment read feeds both sets.
    // Slot rows are permuted, but all 64 slots are processed identically.
    f32x4 accS[2][4];
#pragma unroll
    for (int nt = 0; nt < 4; ++nt) {
#pragma unroll
      for (int s = 0; s < 2; ++s)
#pragma unroll
        for (int i = 0; i < 4; ++i) accS[s][nt][i] = 0.f;
      const short8 kh0 = *reinterpret_cast<const short8*>(&sKh[cur][nt * 16 + ln][qd * 8]);
      const short8 kh1 = *reinterpret_cast<const short8*>(&sKh[cur][nt * 16 + ln][32 + qd * 8]);
      const short8 kl0 = *reinterpret_cast<const short8*>(&sKl[cur][nt * 16 + ln][qd * 8]);
      const short8 kl1 = *reinterpret_cast<const short8*>(&sKl[cur][nt * 16 + ln][32 + qd * 8]);
#pragma unroll
      for (int s = 0; s < 2; ++s) {
        accS[s][nt] = mfma16(kh0, bqh[s][0], accS[s][nt]);
        accS[s][nt] = mfma16(kh1, bqh[s][1], accS[s][nt]);
        accS[s][nt] = mfma16(kh0, bql[s][0], accS[s][nt]);
        accS[s][nt] = mfma16(kh1, bql[s][1], accS[s][nt]);
        accS[s][nt] = mfma16(kl0, bqh[s][0], accS[s][nt]);
        accS[s][nt] = mfma16(kl1, bqh[s][1], accS[s][nt]);
      }
    }

    // per-lane online softmax (lane owns q-row = ln of its set), exp2 domain
    uint pkd[2][4][2];
#pragma unroll
    for (int s = 0; s < 2; ++s) {
      float tmax = fmaxf(
          fmaxf(fmaxf(accS[s][0][0], accS[s][0][1]), fmaxf(accS[s][0][2], accS[s][0][3])),
          fmaxf(fmaxf(accS[s][1][0], accS[s][1][1]), fmaxf(accS[s][1][2], accS[s][1][3])));
      tmax = fmaxf(tmax, fmaxf(
          fmaxf(fmaxf(accS[s][2][0], accS[s][2][1]), fmaxf(accS[s][2][2], accS[s][2][3])),
          fmaxf(fmaxf(accS[s][3][0], accS[s][3][1]), fmaxf(accS[s][3][2], accS[s][3][3]))));
      tmax = fmaxf(tmax, __shfl_xor(tmax, 16));
      tmax = fmaxf(tmax, __shfl_xor(tmax, 32));
      const float mnew  = fmaxf(m_run[s], tmax);
      const float alpha = exp2f(m_run[s] - mnew);
      m_run[s] = mnew;
#pragma unroll
      for (int nt = 0; nt < 4; ++nt) {
        const float p0 = exp2f(accS[s][nt][0] - mnew);
        const float p1 = exp2f(accS[s][nt][1] - mnew);
        const float p2 = exp2f(accS[s][nt][2] - mnew);
        const float p3 = exp2f(accS[s][nt][3] - mnew);
        pkd[s][nt][0] = pack_bf16(p0, p1);
        pkd[s][nt][1] = pack_bf16(p2, p3);
#pragma unroll
        for (int i = 0; i < 4; ++i) accO[s][nt][i] *= alpha;
      }
      accL[s][0] *= alpha;
    }

    // O^T += V^T · P^T ; l += 1~ · P^T — P^T frag is pure register renaming
    // thanks to the permuted K staging (no cross-lane ops).
#pragma unroll
    for (int kt2 = 0; kt2 < 2; ++kt2) {
      short8 pfrag[2];
#pragma unroll
      for (int s = 0; s < 2; ++s) {
        uint4 du;
        du.x = pkd[s][kt2][0];
        du.y = pkd[s][kt2][1];
        du.z = pkd[s][kt2 + 2][0];
        du.w = pkd[s][kt2 + 2][1];
        pfrag[s] = *reinterpret_cast<short8*>(&du);
      }
#pragma unroll
      for (int nt2 = 0; nt2 < 4; ++nt2) {
        const short8 vA = *reinterpret_cast<const short8*>(
            &sVt[cur][nt2 * 16 + ln][kt2 * 32 + qd * 8]);
        accO[0][nt2] = mfma16(vA, pfrag[0], accO[0][nt2]);
        accO[1][nt2] = mfma16(vA, pfrag[1], accO[1][nt2]);
      }
      accL[0] = mfma16(afr1, pfrag[0], accL[0]);
      accL[1] = mfma16(afr1, pfrag[1], accL[1]);
    }

    if (it + 1 < NIT) {
      STORE_TILES(cur ^ 1);   // drain prefetched tile into the other buffer
      __syncthreads();        // single barrier per iter (double-buffered)
    }
  }
#undef LOAD_TILES
#undef STORE_TILES

  // epilogue per set: lane holds q-row = qrow0 + s*16 + ln
#pragma unroll
  for (int s = 0; s < 2; ++s) {
    const int qrow = qrow0 + s * 16 + ln;
    ushort* Ob = Opart + ((size_t)sg * SEQ + qrow) * DH;
#pragma unroll
    for (int nt = 0; nt < 4; ++nt) {
      ushort op[4] __attribute__((aligned(8)));
#pragma unroll
      for (int r = 0; r < 4; ++r) op[r] = bf16_of(accO[s][nt][r]);
      *reinterpret_cast<us4*>(Ob + nt * 16 + qd * 4) =
          *reinterpret_cast<us4*>(op);
    }
    if (qd == 0) {
      Mpart[(size_t)sg * SEQ + qrow] = m_run[s];
      Lpart[(size_t)sg * SEQ + qrow] = accL[s][0];
    }
  }
}

// ---------------------------------------------------------------------------
// Kernel 3: merge of the 8 seq-split partials (exp2 domain), vectorized x4.
// ---------------------------------------------------------------------------
__global__ __launch_bounds__(256) void merge_kernel(
    const ushort* __restrict__ Opart, const float* __restrict__ Mpart,
    const float* __restrict__ Lpart, float* __restrict__ out) {
  const int idx = blockIdx.x * 256 + threadIdx.x;   // 0 .. SEQ*16
  const int row = idx >> 4;
  const int c4  = (idx & 15) * 4;

  float m[SG];
  float M = -INFINITY;
#pragma unroll
  for (int i = 0; i < SG; ++i) {
    m[i] = Mpart[(size_t)i * SEQ + row];
    M = fmaxf(M, m[i]);
  }
  float L = 0.f;
  float a0 = 0.f, a1 = 0.f, a2 = 0.f, a3 = 0.f;
#pragma unroll
  for (int i = 0; i < SG; ++i) {
    const float w = exp2f(m[i] - M);
    L += w * Lpart[(size_t)i * SEQ + row];
    const us4 o = *reinterpret_cast<const us4*>(
        Opart + ((size_t)i * SEQ + row) * DH + c4);
    a0 += w * f_of_bf16(o[0]);
    a1 += w * f_of_bf16(o[1]);
    a2 += w * f_of_bf16(o[2]);
    a3 += w * f_of_bf16(o[3]);
  }
  const float rL = 1.0f / L;
  float4 res = make_float4(a0 * rL, a1 * rL, a2 * rL, a3 * rL);
  *reinterpret_cast<float4*>(out + (size_t)row * DH + c4) = res;
}

// ---------------------------------------------------------------------------
extern "C" void kernel_launch(void* const* d_in, const int* in_sizes, int n_in,
                              void* d_out, int out_size, void* d_ws, size_t ws_size,
                              hipStream_t stream) {
  const float* x  = (const float*)d_in[0];
  const float* Wq = (const float*)d_in[1];
  const float* Wk = (const float*)d_in[2];
  const float* Wv = (const float*)d_in[3];
  float* out = (float*)d_out;

  // workspace layout — 14,155,776 B (R2..R11-proven size).
  const size_t S64 = (size_t)SEQ * DH;        // 524288
  ushort* Qh = (ushort*)d_ws;
  ushort* Ql = Qh + S64;
  ushort* Kh = Ql + S64;
  ushort* Kl = Kh + S64;
  ushort* Vt = Kl + S64;
  ushort* Op = Vt + S64;                      // [SG][SEQ][DH] bf16
  ushort* Wth = Op;                           // alias (3*64*512 elems)
  ushort* Wtl = Wth + (size_t)3 * 64 * 512;
  float*  Mp = (float*)(Op + (size_t)SG * S64);
  float*  Lp = Mp + (size_t)SG * SEQ;

  prep_kernel<<<24, 256, 0, stream>>>(Wq, Wk, Wv, Wth, Wtl);
  pgemm_kernel<<<SEQ / 16, 256, 0, stream>>>(x, Wth, Wtl, Qh, Ql, Kh, Kl, Vt);
  flash_kernel<<<(SEQ / 128) * SG, 256, 0, stream>>>(Qh, Ql, Kh, Kl, Vt, Op, Mp, Lp);
  merge_kernel<<<(SEQ * 16) / 256, 256, 0, stream>>>(Op, Mp, Lp, out);
}

// Round 13
// 130.204 us; speedup vs baseline: 3.7827x; 1.0999x over previous
//
#include <hip/hip_runtime.h>
#include <hip/hip_bf16.h>
#include <math.h>

#define SEQ 8192
#define DIN 512
#define DH  64
#define SG  8                 // sequence splits
#define CHUNK (SEQ / SG)      // 1024 K-rows per flash block
#define BK  64                // K/V rows per iteration
#define NIT (CHUNK / BK)      // 16 iterations
#define LDP 72                // padded LDS row stride (bf16)
#define SXP 516               // padded fp32 x row stride (pgemm)

typedef float f32x4 __attribute__((ext_vector_type(4)));
typedef short short8 __attribute__((ext_vector_type(8)));
typedef ushort us4 __attribute__((ext_vector_type(4)));

static __device__ __forceinline__ ushort bf16_of(float v) {
  __hip_bfloat16 h = __float2bfloat16(v);
  return *reinterpret_cast<ushort*>(&h);
}
static __device__ __forceinline__ float f_of_bf16(ushort u) {
  __hip_bfloat16 h;
  *reinterpret_cast<ushort*>(&h) = u;
  return __bfloat162float(h);
}
static __device__ __forceinline__ f32x4 mfma16(short8 a, short8 b, f32x4 c) {
  return __builtin_amdgcn_mfma_f32_16x16x32_bf16(a, b, c, 0, 0, 0);
}
static __device__ __forceinline__ uint pack_bf16(float a, float b) {
  __hip_bfloat162 h2 = __float22bfloat162_rn(make_float2(a, b));
  return *reinterpret_cast<uint*>(&h2);
}
// K-row permutation (R12-proven): physical row p -> LDS slot, chosen so the
// S^T C-layout ownership coincides with the PV B-operand k-ownership,
// making the P^T fragment pure register renaming.
static __device__ __forceinline__ int slot_of(int p) {
  return ((((p >> 2) & 1) * 2 + (p >> 5)) << 4) | (((p >> 3) & 3) << 2) | (p & 3);
}

// ---------------------------------------------------------------------------
// Kernel 1 (pgemm v4): prep FOLDED IN.  W is read directly in fp32 and the
// scale (+ 0.125*log2e for Wq) / transpose / hi-lo split happen in-register
// at fragment-build time — bit-identical arithmetic to the old prep path,
// but the prep dispatch (~14 us incl. overhead, R10 vs R5..R12 datum) is
// gone.  Register-prefetch ping-pong on the 32 fp32 W values per (kt,m)
// group (R10-proven decoupling recipe).
// ---------------------------------------------------------------------------
__global__ __launch_bounds__(256, 2) void pgemm_kernel(
    const float* __restrict__ x,  const float* __restrict__ Wq,
    const float* __restrict__ Wk, const float* __restrict__ Wv,
    ushort* __restrict__ Qh, ushort* __restrict__ Ql,
    ushort* __restrict__ Kh, ushort* __restrict__ Kl,
    ushort* __restrict__ Vt) {
  __shared__ float sx[16][SXP];               // 33 KB; reused as merge buf
  float* mb = &sx[0][0];

  const int tid = threadIdx.x;
  const int wv = tid >> 6, lane = tid & 63;
  const int ln = lane & 15, qd = lane >> 4;
  const int rb = blockIdx.x * 16;

  {
    const float4* xg = reinterpret_cast<const float4*>(x + (size_t)rb * DIN);
#pragma unroll
    for (int j = 0; j < 8; ++j) {
      const int idx = tid + 256 * j;
      const int row = idx >> 7;
      const int col = (idx & 127) * 4;
      *reinterpret_cast<float4*>(&sx[row][col]) = xg[idx];
    }
  }
  __syncthreads();

  f32x4 acc[3][4];
#pragma unroll
  for (int m = 0; m < 3; ++m)
#pragma unroll
    for (int nt = 0; nt < 4; ++nt)
#pragma unroll
      for (int i = 0; i < 4; ++i) acc[m][nt][i] = 0.f;

  const int kb = wv * 128;
  // per-lane base offset into W[k][n] (row-major 512x64): k = kb+qd*8, n = ln
  const int wbase = (kb + qd * 8) * 64 + ln;

  float wf[2][32];
#define LDW(kt_, m_, buf_)                                                     \
  do {                                                                         \
    const float* W_ = ((m_) == 0) ? Wq : (((m_) == 1) ? Wk : Wv);              \
    const int o_ = wbase + (kt_) * 32 * 64;                                    \
    _Pragma("unroll") for (int nt = 0; nt < 4; ++nt)                           \
      _Pragma("unroll") for (int j = 0; j < 8; ++j)                            \
        wf[buf_][nt * 8 + j] = W_[o_ + j * 64 + nt * 16];                      \
  } while (0)

  LDW(0, 0, 0);
#pragma unroll
  for (int kt = 0; kt < 4; ++kt) {
    const int k0 = kb + kt * 32;
    float xs[8];
    *reinterpret_cast<float4*>(xs) =
        *reinterpret_cast<const float4*>(&sx[ln][k0 + qd * 8]);
    *reinterpret_cast<float4*>(xs + 4) =
        *reinterpret_cast<const float4*>(&sx[ln][k0 + qd * 8 + 4]);
    ushort ah[8] __attribute__((aligned(16)));
    ushort al[8] __attribute__((aligned(16)));
#pragma unroll
    for (int j = 0; j < 8; ++j) {
      const ushort h = bf16_of(xs[j]);
      ah[j] = h;
      al[j] = bf16_of(xs[j] - f_of_bf16(h));
    }
    const short8 Ah = *reinterpret_cast<short8*>(ah);
    const short8 Al = *reinterpret_cast<short8*>(al);
#pragma unroll
    for (int m = 0; m < 3; ++m) {
      const int g = kt * 3 + m;               // compile-time (unrolled)
      const int buf = g & 1;
      if (g < 11) {
        const int gn = g + 1;
        LDW(gn / 3, gn % 3, buf ^ 1);         // prefetch next group's W fp32
      }
      const float scale = (m == 0) ? 0.125f * 1.44269504088896f : 1.0f;
#pragma unroll
      for (int nt = 0; nt < 4; ++nt) {
        ushort bh8[8] __attribute__((aligned(16)));
        ushort bl8[8] __attribute__((aligned(16)));
#pragma unroll
        for (int j = 0; j < 8; ++j) {
          const float v = wf[buf][nt * 8 + j] * scale;
          const ushort h = bf16_of(v);
          bh8[j] = h;
          bl8[j] = bf16_of(v - f_of_bf16(h));
        }
        const short8 bh = *reinterpret_cast<short8*>(bh8);
        const short8 bl = *reinterpret_cast<short8*>(bl8);
        acc[m][nt] = mfma16(Ah, bh, acc[m][nt]);
        acc[m][nt] = mfma16(Ah, bl, acc[m][nt]);
        acc[m][nt] = mfma16(Al, bh, acc[m][nt]);
      }
    }
  }
#undef LDW

  const int eidx = (qd * 4) * 64 + ln;
  __syncthreads();
  if (wv >= 2) {
    float* b = mb + (size_t)(wv - 2) * 3072;
#pragma unroll
    for (int m = 0; m < 3; ++m)
#pragma unroll
      for (int nt = 0; nt < 4; ++nt)
#pragma unroll
        for (int r = 0; r < 4; ++r)
          b[m * 1024 + eidx + r * 64 + nt * 16] = acc[m][nt][r];
  }
  __syncthreads();
  if (wv < 2) {
    const float* b = mb + (size_t)wv * 3072;
#pragma unroll
    for (int m = 0; m < 3; ++m)
#pragma unroll
      for (int nt = 0; nt < 4; ++nt)
#pragma unroll
        for (int r = 0; r < 4; ++r)
          acc[m][nt][r] += b[m * 1024 + eidx + r * 64 + nt * 16];
  }
  __syncthreads();
  if (wv == 1) {
#pragma unroll
    for (int m = 0; m < 3; ++m)
#pragma unroll
      for (int nt = 0; nt < 4; ++nt)
#pragma unroll
        for (int r = 0; r < 4; ++r)
          mb[m * 1024 + eidx + r * 64 + nt * 16] = acc[m][nt][r];
  }
  __syncthreads();
  if (wv == 0) {
#pragma unroll
    for (int m = 0; m < 3; ++m)
#pragma unroll
      for (int nt = 0; nt < 4; ++nt)
#pragma unroll
        for (int r = 0; r < 4; ++r)
          acc[m][nt][r] += mb[m * 1024 + eidx + r * 64 + nt * 16];

#pragma unroll
    for (int m = 0; m < 2; ++m) {
      ushort* H = (m == 0) ? Qh : Kh;
      ushort* L = (m == 0) ? Ql : Kl;
#pragma unroll
      for (int nt = 0; nt < 4; ++nt)
#pragma unroll
        for (int r = 0; r < 4; ++r) {
          const float v = acc[m][nt][r];
          const int row = rb + qd * 4 + r;
          const int col = nt * 16 + ln;
          const ushort h = bf16_of(v);
          H[(size_t)row * DH + col] = h;
          L[(size_t)row * DH + col] = bf16_of(v - f_of_bf16(h));
        }
    }
#pragma unroll
    for (int nt = 0; nt < 4; ++nt) {
      ushort vp[4] __attribute__((aligned(8)));
#pragma unroll
      for (int r = 0; r < 4; ++r) vp[r] = bf16_of(acc[2][nt][r]);
      *reinterpret_cast<us4*>(Vt + (size_t)(nt * 16 + ln) * SEQ + rb + qd * 4) =
          *reinterpret_cast<us4*>(vp);
    }
  }
}

// ---------------------------------------------------------------------------
// Kernel 2 (flash v5, R12-proven, UNCHANGED): 2 Q-sets/wave + permuted K
// staging (gather-free P^T) + double-buffered LDS (one barrier per iter).
// ---------------------------------------------------------------------------
__global__ __launch_bounds__(256, 2) void flash_kernel(
    const ushort* __restrict__ Qh, const ushort* __restrict__ Ql,
    const ushort* __restrict__ Kh, const ushort* __restrict__ Kl,
    const ushort* __restrict__ Vt,
    ushort* __restrict__ Opart, float* __restrict__ Mpart,
    float* __restrict__ Lpart) {
  __shared__ __attribute__((aligned(16))) ushort sKh[2][BK][LDP];  // 18.4 KB
  __shared__ __attribute__((aligned(16))) ushort sKl[2][BK][LDP];  // 18.4 KB
  __shared__ __attribute__((aligned(16))) ushort sVt[2][DH][LDP];  // 18.4 KB

  const int tid  = threadIdx.x;
  const int wv   = tid >> 6;
  const int lane = tid & 63;
  const int ln   = lane & 15;
  const int qd   = lane >> 4;
  const int bid  = blockIdx.x;
  const int sg   = bid & 7;
  const int qt   = bid >> 3;        // 0..63 (128-row Q tiles)
  const int qrow0  = qt * 128 + wv * 32;   // set s adds s*16
  const int k0base = sg * CHUNK;

  const int r0 = tid >> 3, g0 = (tid & 7) * 8;
  const int r1 = r0 + 32,  g1 = g0;
  const int sr0 = slot_of(r0), sr1 = slot_of(r1);   // permuted K slots

  const ushort one_u = (ln == 0) ? (ushort)0x3F80 : (ushort)0;
  short8 afr1;
#pragma unroll
  for (int j = 0; j < 8; ++j) afr1[j] = (short)one_u;

  short8 bqh[2][2], bql[2][2];
#pragma unroll
  for (int s = 0; s < 2; ++s)
#pragma unroll
    for (int kt = 0; kt < 2; ++kt) {
      bqh[s][kt] = *reinterpret_cast<const short8*>(
          Qh + (size_t)(qrow0 + s * 16 + ln) * DH + kt * 32 + qd * 8);
      bql[s][kt] = *reinterpret_cast<const short8*>(
          Ql + (size_t)(qrow0 + s * 16 + ln) * DH + kt * 32 + qd * 8);
    }

  f32x4 accO[2][4], accL[2];
  float m_run[2] = {-INFINITY, -INFINITY};
#pragma unroll
  for (int s = 0; s < 2; ++s) {
#pragma unroll
    for (int nt = 0; nt < 4; ++nt)
#pragma unroll
      for (int i = 0; i < 4; ++i) accO[s][nt][i] = 0.f;
#pragma unroll
    for (int i = 0; i < 4; ++i) accL[s][i] = 0.f;
  }

  uint4 pk0, pk1, pl0, pl1, pv0, pv1;
#define LOAD_TILES(k0_)                                                        \
  do {                                                                         \
    pk0 = *reinterpret_cast<const uint4*>(Kh + (size_t)((k0_) + r0) * DH + g0);\
    pk1 = *reinterpret_cast<const uint4*>(Kh + (size_t)((k0_) + r1) * DH + g1);\
    pl0 = *reinterpret_cast<const uint4*>(Kl + (size_t)((k0_) + r0) * DH + g0);\
    pl1 = *reinterpret_cast<const uint4*>(Kl + (size_t)((k0_) + r1) * DH + g1);\
    pv0 = *reinterpret_cast<const uint4*>(Vt + (size_t)r0 * SEQ + (k0_) + g0); \
    pv1 = *reinterpret_cast<const uint4*>(Vt + (size_t)r1 * SEQ + (k0_) + g1); \
  } while (0)
#define STORE_TILES(b_)                                                        \
  do {                                                                         \
    *reinterpret_cast<uint4*>(&sKh[b_][sr0][g0]) = pk0;                        \
    *reinterpret_cast<uint4*>(&sKh[b_][sr1][g1]) = pk1;                        \
    *reinterpret_cast<uint4*>(&sKl[b_][sr0][g0]) = pl0;                        \
    *reinterpret_cast<uint4*>(&sKl[b_][sr1][g1]) = pl1;                        \
    *reinterpret_cast<uint4*>(&sVt[b_][r0][g0])  = pv0;                        \
    *reinterpret_cast<uint4*>(&sVt[b_][r1][g1])  = pv1;                        \
  } while (0)

  LOAD_TILES(k0base);
  STORE_TILES(0);
  __syncthreads();

  for (int it = 0; it < NIT; ++it) {
    const int cur = it & 1;
    const int k0n = k0base + ((it + 1 < NIT) ? (it + 1) : it) * BK;
    LOAD_TILES(k0n);          // global loads for next iter, hidden by compute

    f32x4 accS[2][4];
#pragma unroll
    for (int nt = 0; nt < 4; ++nt) {
#pragma unroll
      for (int s = 0; s < 2; ++s)
#pragma unroll
        for (int i = 0; i < 4; ++i) accS[s][nt][i] = 0.f;
      const short8 kh0 = *reinterpret_cast<const short8*>(&sKh[cur][nt * 16 + ln][qd * 8]);
      const short8 kh1 = *reinterpret_cast<const short8*>(&sKh[cur][nt * 16 + ln][32 + qd * 8]);
      const short8 kl0 = *reinterpret_cast<const short8*>(&sKl[cur][nt * 16 + ln][qd * 8]);
      const short8 kl1 = *reinterpret_cast<const short8*>(&sKl[cur][nt * 16 + ln][32 + qd * 8]);
#pragma unroll
      for (int s = 0; s < 2; ++s) {
        accS[s][nt] = mfma16(kh0, bqh[s][0], accS[s][nt]);
        accS[s][nt] = mfma16(kh1, bqh[s][1], accS[s][nt]);
        accS[s][nt] = mfma16(kh0, bql[s][0], accS[s][nt]);
        accS[s][nt] = mfma16(kh1, bql[s][1], accS[s][nt]);
        accS[s][nt] = mfma16(kl0, bqh[s][0], accS[s][nt]);
        accS[s][nt] = mfma16(kl1, bqh[s][1], accS[s][nt]);
      }
    }

    uint pkd[2][4][2];
#pragma unroll
    for (int s = 0; s < 2; ++s) {
      float tmax = fmaxf(
          fmaxf(fmaxf(accS[s][0][0], accS[s][0][1]), fmaxf(accS[s][0][2], accS[s][0][3])),
          fmaxf(fmaxf(accS[s][1][0], accS[s][1][1]), fmaxf(accS[s][1][2], accS[s][1][3])));
      tmax = fmaxf(tmax, fmaxf(
          fmaxf(fmaxf(accS[s][2][0], accS[s][2][1]), fmaxf(accS[s][2][2], accS[s][2][3])),
          fmaxf(fmaxf(accS[s][3][0], accS[s][3][1]), fmaxf(accS[s][3][2], accS[s][3][3]))));
      tmax = fmaxf(tmax, __shfl_xor(tmax, 16));
      tmax = fmaxf(tmax, __shfl_xor(tmax, 32));
      const float mnew  = fmaxf(m_run[s], tmax);
      const float alpha = exp2f(m_run[s] - mnew);
      m_run[s] = mnew;
#pragma unroll
      for (int nt = 0; nt < 4; ++nt) {
        const float p0 = exp2f(accS[s][nt][0] - mnew);
        const float p1 = exp2f(accS[s][nt][1] - mnew);
        const float p2 = exp2f(accS[s][nt][2] - mnew);
        const float p3 = exp2f(accS[s][nt][3] - mnew);
        pkd[s][nt][0] = pack_bf16(p0, p1);
        pkd[s][nt][1] = pack_bf16(p2, p3);
#pragma unroll
        for (int i = 0; i < 4; ++i) accO[s][nt][i] *= alpha;
      }
      accL[s][0] *= alpha;
    }

    // O^T += V^T · P^T ; l += 1~ · P^T — P^T frag is pure register renaming
#pragma unroll
    for (int kt2 = 0; kt2 < 2; ++kt2) {
      short8 pfrag[2];
#pragma unroll
      for (int s = 0; s < 2; ++s) {
        uint4 du;
        du.x = pkd[s][kt2][0];
        du.y = pkd[s][kt2][1];
        du.z = pkd[s][kt2 + 2][0];
        du.w = pkd[s][kt2 + 2][1];
        pfrag[s] = *reinterpret_cast<short8*>(&du);
      }
#pragma unroll
      for (int nt2 = 0; nt2 < 4; ++nt2) {
        const short8 vA = *reinterpret_cast<const short8*>(
            &sVt[cur][nt2 * 16 + ln][kt2 * 32 + qd * 8]);
        accO[0][nt2] = mfma16(vA, pfrag[0], accO[0][nt2]);
        accO[1][nt2] = mfma16(vA, pfrag[1], accO[1][nt2]);
      }
      accL[0] = mfma16(afr1, pfrag[0], accL[0]);
      accL[1] = mfma16(afr1, pfrag[1], accL[1]);
    }

    if (it + 1 < NIT) {
      STORE_TILES(cur ^ 1);
      __syncthreads();
    }
  }
#undef LOAD_TILES
#undef STORE_TILES

#pragma unroll
  for (int s = 0; s < 2; ++s) {
    const int qrow = qrow0 + s * 16 + ln;
    ushort* Ob = Opart + ((size_t)sg * SEQ + qrow) * DH;
#pragma unroll
    for (int nt = 0; nt < 4; ++nt) {
      ushort op[4] __attribute__((aligned(8)));
#pragma unroll
      for (int r = 0; r < 4; ++r) op[r] = bf16_of(accO[s][nt][r]);
      *reinterpret_cast<us4*>(Ob + nt * 16 + qd * 4) =
          *reinterpret_cast<us4*>(op);
    }
    if (qd == 0) {
      Mpart[(size_t)sg * SEQ + qrow] = m_run[s];
      Lpart[(size_t)sg * SEQ + qrow] = accL[s][0];
    }
  }
}

// ---------------------------------------------------------------------------
// Kernel 3: merge of the 8 seq-split partials (exp2 domain), vectorized x4.
// ---------------------------------------------------------------------------
__global__ __launch_bounds__(256) void merge_kernel(
    const ushort* __restrict__ Opart, const float* __restrict__ Mpart,
    const float* __restrict__ Lpart, float* __restrict__ out) {
  const int idx = blockIdx.x * 256 + threadIdx.x;   // 0 .. SEQ*16
  const int row = idx >> 4;
  const int c4  = (idx & 15) * 4;

  float m[SG];
  float M = -INFINITY;
#pragma unroll
  for (int i = 0; i < SG; ++i) {
    m[i] = Mpart[(size_t)i * SEQ + row];
    M = fmaxf(M, m[i]);
  }
  float L = 0.f;
  float a0 = 0.f, a1 = 0.f, a2 = 0.f, a3 = 0.f;
#pragma unroll
  for (int i = 0; i < SG; ++i) {
    const float w = exp2f(m[i] - M);
    L += w * Lpart[(size_t)i * SEQ + row];
    const us4 o = *reinterpret_cast<const us4*>(
        Opart + ((size_t)i * SEQ + row) * DH + c4);
    a0 += w * f_of_bf16(o[0]);
    a1 += w * f_of_bf16(o[1]);
    a2 += w * f_of_bf16(o[2]);
    a3 += w * f_of_bf16(o[3]);
  }
  const float rL = 1.0f / L;
  float4 res = make_float4(a0 * rL, a1 * rL, a2 * rL, a3 * rL);
  *reinterpret_cast<float4*>(out + (size_t)row * DH + c4) = res;
}

// ---------------------------------------------------------------------------
extern "C" void kernel_launch(void* const* d_in, const int* in_sizes, int n_in,
                              void* d_out, int out_size, void* d_ws, size_t ws_size,
                              hipStream_t stream) {
  const float* x  = (const float*)d_in[0];
  const float* Wq = (const float*)d_in[1];
  const float* Wk = (const float*)d_in[2];
  const float* Wv = (const float*)d_in[3];
  float* out = (float*)d_out;

  // workspace layout — 14,155,776 B (R2..R12-proven size).
  const size_t S64 = (size_t)SEQ * DH;        // 524288
  ushort* Qh = (ushort*)d_ws;
  ushort* Ql = Qh + S64;
  ushort* Kh = Ql + S64;
  ushort* Kl = Kh + S64;
  ushort* Vt = Kl + S64;
  ushort* Op = Vt + S64;                      // [SG][SEQ][DH] bf16
  float*  Mp = (float*)(Op + (size_t)SG * S64);
  float*  Lp = Mp + (size_t)SG * SEQ;

  pgemm_kernel<<<SEQ / 16, 256, 0, stream>>>(x, Wq, Wk, Wv, Qh, Ql, Kh, Kl, Vt);
  flash_kernel<<<(SEQ / 128) * SG, 256, 0, stream>>>(Qh, Ql, Kh, Kl, Vt, Op, Mp, Lp);
  merge_kernel<<<(SEQ * 16) / 256, 256, 0, stream>>>(Op, Mp, Lp, out);
}